// Round 5
// baseline (837.532 us; speedup 1.0000x reference)
//
#include <hip/hip_runtime.h>
#include <hip/hip_bf16.h>
#include <stdint.h>

// ---------------------------------------------------------------------------
// AttentionBlock fast path. This round: kv-gemm fused per-block (one X-tile
// staging feeds BOTH W_v and W_k panels -> 2x MFMA per staged byte) + LDS
// read-swizzle with pre-swizzled global source (rule #21 / m173) to kill the
// 8-way ds_read_b128 bank conflict. q/f projections keep the round-4 gemm128
// (counted-vmcnt depth-3). Attention/norm/finalize unchanged.
// ---------------------------------------------------------------------------

typedef __attribute__((ext_vector_type(8))) short short8;
typedef __attribute__((ext_vector_type(4))) float floatx4;

__device__ __forceinline__ float bf2f(short h) {
    union { unsigned u; float f; } c;
    c.u = ((unsigned)(unsigned short)h) << 16;
    return c.f;
}
__device__ __forceinline__ short f2bf(float f) {
    union { float f; unsigned u; } c;
    c.f = f;
    unsigned u = c.u + 0x7fffu + ((c.u >> 16) & 1u);  // RNE
    return (short)(u >> 16);
}

__device__ __forceinline__ void async_cp16(const short* g, short* l) {
    __builtin_amdgcn_global_load_lds(
        (const __attribute__((address_space(1))) unsigned int*)g,
        (__attribute__((address_space(3))) unsigned int*)l, 16, 0, 0);
}

__device__ __forceinline__ short8 cvt8load(const float* p) {
    float4 f0 = *(const float4*)(p);
    float4 f1 = *(const float4*)(p + 4);
    short8 r;
    r[0] = f2bf(f0.x); r[1] = f2bf(f0.y); r[2] = f2bf(f0.z); r[3] = f2bf(f0.w);
    r[4] = f2bf(f1.x); r[5] = f2bf(f1.y); r[6] = f2bf(f1.z); r[7] = f2bf(f1.w);
    return r;
}
__device__ __forceinline__ short8 cvt8guard(const float* row, int c0, int Kin) {
    short8 r;
#pragma unroll
    for (int j = 0; j < 8; j++) {
        int c = c0 + j;
        r[j] = (c < Kin) ? f2bf(row[c]) : (short)0;
    }
    return r;
}

// ---------------- convert fp32 -> bf16 with K padding ----------------------
__global__ __launch_bounds__(256) void cvt_pad(const float* __restrict__ in,
                                               short* __restrict__ out,
                                               int kin, int kout) {
    long row = blockIdx.x;
    const float* src = in + row * (long)kin;
    short* dst = out + row * (long)kout;
    for (int c = threadIdx.x; c < kout; c += 256)
        dst[c] = (c < kin) ? f2bf(src[c]) : (short)0;
}

// ---------------- fused dual-output BT GEMM: 128 rows x {Y0,Y1} x 128 cols -
// Per block: stage X-tile ONCE, multiply against W0 and W1 128-col panels.
// 32 MFMA per K-step per wave vs 6 staging VMEM ops (2.7x the old ratio).
// LDS tiles [128][32] shorts with XOR read-swizzle f(S)=S^(((S>>6)&7)<<4);
// global_load_lds dest stays LINEAR, source addresses carry the inverse
// permutation (m173 / rule #21). Counted vmcnt (never 0 in main loop).
__global__ __launch_bounds__(256, 2)
void gemm128x2(const short* __restrict__ X,
               const short* __restrict__ W0, const short* __restrict__ W1,
               const float* __restrict__ bias0, const float* __restrict__ bias1,
               short* __restrict__ Y0, short* __restrict__ Y1,
               float* __restrict__ st0, float* __restrict__ st1,
               int N, int Kp, const int* __restrict__ lens, int Lshift,
               int nShift)
{
    // 3 bufs x (At | B0 | B1) x 4096 shorts = 36864 sh = 73728 B.
    __shared__ short SH[36864];
    const int lin = blockIdx.x;
    const int xcd = lin & 7, sl = lin >> 3;
    const int nb = sl & ((1 << nShift) - 1);
    const int ms = sl >> nShift;
    const int m0 = (ms * 8 + xcd) * 128;
    const int n0 = nb * 128;

    const int tid = threadIdx.x;
    const int l = tid & 63, w = tid >> 6;
    const int quad = l >> 4, l15 = l & 15;
    const int wr = w & 1, wc = w >> 1;
    const int mo = wr * 64, no = wc * 64;    // wave's 64x64 quadrant

    floatx4 acc0[4][4], acc1[4][4];
#pragma unroll
    for (int i = 0; i < 4; i++)
#pragma unroll
        for (int j = 0; j < 4; j++) {
            acc0[i][j] = (floatx4){0.f, 0.f, 0.f, 0.f};
            acc1[i][j] = (floatx4){0.f, 0.f, 0.f, 0.f};
        }

    // -------- source pre-swizzle (inverse of read-swizzle) --------
    // Thread covers LINEAR LDS bytes L = tid*16 + c*4096 (c=0,1).
    // Element with pre-swizzle addr S lands at L = S ^ (((S>>6)&7)<<4).
    // Inverse: S4=L4^L6^L8, S5=L5^L7, S6=L6^L8.
    int srow[2], scolS[2];                   // row, col (shorts) in [128][32]
#pragma unroll
    for (int c = 0; c < 2; c++) {
        int L = tid * 16 + c * 4096;
        int S = L ^ ((((L >> 6) ^ (L >> 8)) & 1) << 4)
                  ^ (((L >> 7) & 1) << 5)
                  ^ (((L >> 8) & 1) << 6);
        srow[c] = S >> 6;
        scolS[c] = (S & 48) >> 1;            // quad*16 B -> shorts
    }
    const short* Xs[2];
    const short* W0s[2];
    const short* W1s[2];
#pragma unroll
    for (int c = 0; c < 2; c++) {
        Xs[c]  = X  + (long)(m0 + srow[c]) * Kp + scolS[c];
        W0s[c] = W0 + (long)(n0 + srow[c]) * Kp + scolS[c];
        W1s[c] = W1 + (long)(n0 + srow[c]) * Kp + scolS[c];
    }
    const int nsteps = Kp >> 5;              // BK = 32, nsteps >= 3

    // swizzled read byte offsets (loop-invariant per lane)
    int rsA[4], rsB[4];
#pragma unroll
    for (int i = 0; i < 4; i++) {
        int rA = mo + i * 16 + l15;
        int rB = no + i * 16 + l15;
        rsA[i] = (rA << 6) ^ ((rA & 7) << 4) ^ (quad << 4);
        rsB[i] = (rB << 6) ^ ((rB & 7) << 4) ^ (quad << 4);
    }

    // stage tile t into buffer buf: 6 VMEM ops per wave
    auto stage = [&](int buf, int t) {
        short* At = SH + buf * 12288;
        short* B0t = At + 4096;
        short* B1t = At + 8192;
        const int ko = t * 32;
#pragma unroll
        for (int c = 0; c < 2; c++)
            async_cp16(Xs[c] + ko, At + c * 2048 + tid * 8);
#pragma unroll
        for (int c = 0; c < 2; c++)
            async_cp16(W0s[c] + ko, B0t + c * 2048 + tid * 8);
#pragma unroll
        for (int c = 0; c < 2; c++)
            async_cp16(W1s[c] + ko, B1t + c * 2048 + tid * 8);
    };

    stage(0, 0);
    if (nsteps > 1) stage(1, 1);
    if (nsteps > 2) stage(2, 2);

    int cur = 0;
    for (int t = 0; t < nsteps; t++) {
        if (t + 2 < nsteps)      asm volatile("s_waitcnt vmcnt(12)" ::: "memory");
        else if (t + 1 < nsteps) asm volatile("s_waitcnt vmcnt(6)" ::: "memory");
        else                     asm volatile("s_waitcnt vmcnt(0)" ::: "memory");
        __builtin_amdgcn_s_barrier();
        __builtin_amdgcn_sched_barrier(0);

        const char* At = (const char*)(SH + cur * 12288);
        const char* B0t = At + 8192;
        const char* B1t = At + 16384;
        short8 af[4], bfr[4];
#pragma unroll
        for (int i = 0; i < 4; i++)
            af[i] = *(const short8*)(At + rsA[i]);
#pragma unroll
        for (int j = 0; j < 4; j++)
            bfr[j] = *(const short8*)(B0t + rsB[j]);
#pragma unroll
        for (int i = 0; i < 4; i++)
#pragma unroll
            for (int j = 0; j < 4; j++)
                acc0[i][j] = __builtin_amdgcn_mfma_f32_16x16x32_bf16(af[i], bfr[j], acc0[i][j], 0, 0, 0);
#pragma unroll
        for (int j = 0; j < 4; j++)
            bfr[j] = *(const short8*)(B1t + rsB[j]);
#pragma unroll
        for (int i = 0; i < 4; i++)
#pragma unroll
            for (int j = 0; j < 4; j++)
                acc1[i][j] = __builtin_amdgcn_mfma_f32_16x16x32_bf16(af[i], bfr[j], acc1[i][j], 0, 0, 0);

        __builtin_amdgcn_sched_barrier(0);
        __builtin_amdgcn_s_barrier();
        if (t + 3 < nsteps) stage(cur, t + 3);
        cur = (cur == 2) ? 0 : cur + 1;
    }

    // ---- epilogue (x2): bias + masked stats + LDS-staged coalesced store --
    const int Lmask = (1 << Lshift) - 1;
    float msk[4][4];
#pragma unroll
    for (int i = 0; i < 4; i++)
#pragma unroll
        for (int r = 0; r < 4; r++) {
            int rg = m0 + mo + i * 16 + quad * 4 + r;
            msk[i][r] = ((rg & Lmask) < lens[rg >> Lshift]) ? 1.f : 0.f;
        }
    short* Cs = SH;

    auto epi = [&](floatx4 (&acc)[4][4], const float* bias, float* stats, short* Y) {
        float bv[4];
#pragma unroll
        for (int j = 0; j < 4; j++) bv[j] = bias[n0 + no + j * 16 + l15];
#pragma unroll
        for (int j = 0; j < 4; j++) {
            float ps = 0.f, pss = 0.f;
#pragma unroll
            for (int i = 0; i < 4; i++)
#pragma unroll
                for (int r = 0; r < 4; r++) {
                    float v = acc[i][j][r] + bv[j];
                    ps += v * msk[i][r];
                    pss += v * v * msk[i][r];
                }
            ps  += __shfl_xor(ps, 16, 64);  ps  += __shfl_xor(ps, 32, 64);
            pss += __shfl_xor(pss, 16, 64); pss += __shfl_xor(pss, 32, 64);
            if (l < 16) {
                atomicAdd(&stats[n0 + no + j * 16 + l15], ps);
                atomicAdd(&stats[N + n0 + no + j * 16 + l15], pss);
            }
        }
#pragma unroll
        for (int pass = 0; pass < 2; pass++) {
            __syncthreads();
            if (wr == pass) {
#pragma unroll
                for (int j = 0; j < 4; j++)
#pragma unroll
                    for (int i = 0; i < 4; i++)
#pragma unroll
                        for (int r = 0; r < 4; r++)
                            Cs[(i * 16 + quad * 4 + r) * 132 + no + j * 16 + l15] =
                                f2bf(acc[i][j][r] + bv[j]);
            }
            __syncthreads();
#pragma unroll
            for (int c = 0; c < 4; c++) {
                int e = c * 2048 + tid * 8;
                int row = e >> 7, col = e & 127;
                short8 vv = *(const short8*)(Cs + row * 132 + col);
                *(short8*)(Y + (long)(m0 + pass * 64 + row) * N + n0 + col) = vv;
            }
        }
    };
    epi(acc0, bias0, st0, Y0);
    epi(acc1, bias1, st1, Y1);
}

// ---------------- BT GEMM (round-4, counted vmcnt): q / f projections ------
__global__ __launch_bounds__(256, 3)
void gemm128(const short* __restrict__ X,
             const short* __restrict__ W0, const short* __restrict__ W1,
             const float* __restrict__ bias0, const float* __restrict__ bias1,
             short* __restrict__ Y0, short* __restrict__ Y1,
             float* __restrict__ st0, float* __restrict__ st1,
             int N, int Kp, const int* __restrict__ lens, int Lshift,
             int nShift, int dual)
{
    __shared__ short SH[24576];
    const int lin = blockIdx.x;
    const int xcd = lin & 7, sl = lin >> 3;
    const int nb = sl & ((1 << nShift) - 1);
    const int ms = sl >> nShift;
    const int m0 = (ms * 8 + xcd) * 128;
    int g = 0, n0;
    if (dual) { g = nb & 1; n0 = (nb >> 1) * 128; } else { n0 = nb * 128; }
    const short* W    = g ? W1 : W0;
    const float* bias = g ? bias1 : bias0;
    short* Y          = g ? Y1 : Y0;
    float* stats      = g ? st1 : st0;

    const int tid = threadIdx.x;
    const int l = tid & 63, w = tid >> 6;
    const int quad = l >> 4, l15 = l & 15;
    const int wr = w & 1, wc = w >> 1;
    const int mo = wr * 64, no = wc * 64;

    floatx4 acc[4][4];
#pragma unroll
    for (int i = 0; i < 4; i++)
#pragma unroll
        for (int j = 0; j < 4; j++) acc[i][j] = (floatx4){0.f, 0.f, 0.f, 0.f};

    const int srow = tid >> 2;
    const int scol = (tid & 3) * 8;
    const short* Xs = X + (long)(m0 + srow) * Kp + scol;
    const short* Ws = W + (long)(n0 + srow) * Kp + scol;
    const long strideR = (long)64 * Kp;
    const int nsteps = Kp >> 5;

    auto stage = [&](int buf, int t) {
        short* At = SH + buf * 8192;
        short* Bt = At + 4096;
        const short* Xk = Xs + t * 32;
        const short* Wk = Ws + t * 32;
        async_cp16(Xk,           At + tid * 8);
        async_cp16(Xk + strideR, At + 2048 + tid * 8);
        async_cp16(Wk,           Bt + tid * 8);
        async_cp16(Wk + strideR, Bt + 2048 + tid * 8);
    };

    stage(0, 0);
    if (nsteps > 1) stage(1, 1);
    if (nsteps > 2) stage(2, 2);

    int cur = 0;
    for (int t = 0; t < nsteps; t++) {
        if (t + 2 < nsteps)      asm volatile("s_waitcnt vmcnt(8)" ::: "memory");
        else if (t + 1 < nsteps) asm volatile("s_waitcnt vmcnt(4)" ::: "memory");
        else                     asm volatile("s_waitcnt vmcnt(0)" ::: "memory");
        __builtin_amdgcn_s_barrier();
        __builtin_amdgcn_sched_barrier(0);

        const short* At = SH + cur * 8192;
        const short* Bt = At + 4096;
        short8 af[4], bfr[4];
#pragma unroll
        for (int i = 0; i < 4; i++)
            af[i] = *(const short8*)(At + (mo + i * 16 + l15) * 32 + quad * 8);
#pragma unroll
        for (int j = 0; j < 4; j++)
            bfr[j] = *(const short8*)(Bt + (no + j * 16 + l15) * 32 + quad * 8);
#pragma unroll
        for (int i = 0; i < 4; i++)
#pragma unroll
            for (int j = 0; j < 4; j++)
                acc[i][j] = __builtin_amdgcn_mfma_f32_16x16x32_bf16(af[i], bfr[j], acc[i][j], 0, 0, 0);

        __builtin_amdgcn_sched_barrier(0);
        __builtin_amdgcn_s_barrier();
        if (t + 3 < nsteps) stage(cur, t + 3);
        cur = (cur == 2) ? 0 : cur + 1;
    }

    const int Lmask = (1 << Lshift) - 1;
    float msk[4][4];
#pragma unroll
    for (int i = 0; i < 4; i++)
#pragma unroll
        for (int r = 0; r < 4; r++) {
            int rg = m0 + mo + i * 16 + quad * 4 + r;
            msk[i][r] = ((rg & Lmask) < lens[rg >> Lshift]) ? 1.f : 0.f;
        }
    float bv[4];
#pragma unroll
    for (int j = 0; j < 4; j++) bv[j] = bias[n0 + no + j * 16 + l15];

#pragma unroll
    for (int j = 0; j < 4; j++) {
        float ps = 0.f, pss = 0.f;
#pragma unroll
        for (int i = 0; i < 4; i++)
#pragma unroll
            for (int r = 0; r < 4; r++) {
                float v = acc[i][j][r] + bv[j];
                ps += v * msk[i][r];
                pss += v * v * msk[i][r];
            }
        ps  += __shfl_xor(ps, 16, 64);  ps  += __shfl_xor(ps, 32, 64);
        pss += __shfl_xor(pss, 16, 64); pss += __shfl_xor(pss, 32, 64);
        if (l < 16) {
            atomicAdd(&stats[n0 + no + j * 16 + l15], ps);
            atomicAdd(&stats[N + n0 + no + j * 16 + l15], pss);
        }
    }

    short* Cs = SH;
#pragma unroll
    for (int pass = 0; pass < 2; pass++) {
        __syncthreads();
        if (wr == pass) {
#pragma unroll
            for (int j = 0; j < 4; j++)
#pragma unroll
                for (int i = 0; i < 4; i++)
#pragma unroll
                    for (int r = 0; r < 4; r++)
                        Cs[(i * 16 + quad * 4 + r) * 132 + no + j * 16 + l15] =
                            f2bf(acc[i][j][r] + bv[j]);
        }
        __syncthreads();
#pragma unroll
        for (int c = 0; c < 4; c++) {
            int e = c * 2048 + tid * 8;
            int row = e >> 7, col = e & 127;
            short8 vv = *(const short8*)(Cs + row * 132 + col);
            *(short8*)(Y + (long)(m0 + pass * 64 + row) * N + n0 + col) = vv;
        }
    }
}

// ---------------- fallback BT GEMM (R1: fused fp32 cvt staging) ------------
template<bool XBF16, bool KAL>
__global__ __launch_bounds__(256, 2)
void gemm_bt(const void* __restrict__ Xp, const float* __restrict__ W,
             const float* __restrict__ bias, short* __restrict__ Y,
             int N, int Kin, int Kp, float* __restrict__ stats,
             const int* __restrict__ lens, int Lshift)
{
    __shared__ short At[128 * 32];
    __shared__ short Bt[128 * 32];
    const int m0 = blockIdx.x * 128;
    const int n0 = blockIdx.y * 128;
    const int tid = threadIdx.x;
    const int w = tid >> 6, l = tid & 63;
    const int quad = l >> 4, l15 = l & 15;
    const int mo = (w & 1) * 64, no = (w >> 1) * 64;

    floatx4 acc[4][4];
#pragma unroll
    for (int i = 0; i < 4; i++)
#pragma unroll
        for (int j = 0; j < 4; j++) acc[i][j] = (floatx4){0.f, 0.f, 0.f, 0.f};

    const int srow = tid >> 2;
    const int sc8 = (tid & 3) * 8;

    for (int k0 = 0; k0 < Kp; k0 += 32) {
        __syncthreads();
        const int c0 = k0 + sc8;
        short8 a0, a1, b0, b1;
        if (XBF16) {
            const short* X = (const short*)Xp;
            a0 = *(const short8*)(X + (long)(m0 + srow) * Kp + c0);
            a1 = *(const short8*)(X + (long)(m0 + 64 + srow) * Kp + c0);
        } else {
            const float* X = (const float*)Xp;
            if (KAL) {
                a0 = cvt8load(X + (long)(m0 + srow) * Kin + c0);
                a1 = cvt8load(X + (long)(m0 + 64 + srow) * Kin + c0);
            } else {
                a0 = cvt8guard(X + (long)(m0 + srow) * Kin, c0, Kin);
                a1 = cvt8guard(X + (long)(m0 + 64 + srow) * Kin, c0, Kin);
            }
        }
        if (KAL) {
            b0 = cvt8load(W + (long)(n0 + srow) * Kin + c0);
            b1 = cvt8load(W + (long)(n0 + 64 + srow) * Kin + c0);
        } else {
            b0 = cvt8guard(W + (long)(n0 + srow) * Kin, c0, Kin);
            b1 = cvt8guard(W + (long)(n0 + 64 + srow) * Kin, c0, Kin);
        }
        *(short8*)(At + srow * 32 + sc8) = a0;
        *(short8*)(At + (64 + srow) * 32 + sc8) = a1;
        *(short8*)(Bt + srow * 32 + sc8) = b0;
        *(short8*)(Bt + (64 + srow) * 32 + sc8) = b1;
        __syncthreads();
        short8 af[4], bfr[4];
#pragma unroll
        for (int i = 0; i < 4; i++) {
            af[i]  = *(const short8*)(At + (mo + i * 16 + l15) * 32 + quad * 8);
            bfr[i] = *(const short8*)(Bt + (no + i * 16 + l15) * 32 + quad * 8);
        }
#pragma unroll
        for (int i = 0; i < 4; i++)
#pragma unroll
            for (int j = 0; j < 4; j++)
                acc[i][j] = __builtin_amdgcn_mfma_f32_16x16x32_bf16(af[i], bfr[j], acc[i][j], 0, 0, 0);
    }

    const int Lmask = (1 << Lshift) - 1;
    float msk[4][4];
#pragma unroll
    for (int i = 0; i < 4; i++)
#pragma unroll
        for (int r = 0; r < 4; r++) {
            int rg = m0 + mo + i * 16 + quad * 4 + r;
            msk[i][r] = ((rg & Lmask) < lens[rg >> Lshift]) ? 1.f : 0.f;
        }
#pragma unroll
    for (int j = 0; j < 4; j++) {
        int colj = n0 + no + j * 16 + l15;
        float bvs = bias[colj];
        float ps = 0.f, pss = 0.f;
#pragma unroll
        for (int i = 0; i < 4; i++)
#pragma unroll
            for (int r = 0; r < 4; r++) {
                int rg = m0 + mo + i * 16 + quad * 4 + r;
                float v = acc[i][j][r] + bvs;
                Y[(long)rg * N + colj] = f2bf(v);
                ps += v * msk[i][r];
                pss += v * v * msk[i][r];
            }
        ps  += __shfl_xor(ps, 16, 64);  ps  += __shfl_xor(ps, 32, 64);
        pss += __shfl_xor(pss, 16, 64); pss += __shfl_xor(pss, 32, 64);
        if (l < 16) {
            atomicAdd(&stats[colj], ps);
            atomicAdd(&stats[N + colj], pss);
        }
    }
}

// ---------------- finalize: stats -> {scale, shift} per channel ------------
__global__ void finalize_stats(float* __restrict__ stats, const float* __restrict__ g,
                               const float* __restrict__ beta,
                               const int* __restrict__ lens, int C)
{
    __shared__ int lred[256];
    int t = threadIdx.x;
    if (t < 256) lred[t] = lens[t];
    __syncthreads();
    for (int s2 = 128; s2 > 0; s2 >>= 1) {
        if (t < s2) lred[t] += lred[t + s2];
        __syncthreads();
    }
    float cnt = (float)lred[0];
    if (t < C) {
        float mean = stats[t] / cnt;
        float var = fmaxf(stats[C + t] / cnt - mean * mean, 0.f);
        float a = rsqrtf(var + 1e-5f) * g[t];
        stats[t] = a;
        stats[C + t] = beta[t] - mean * a;
    }
}

// ---------------- BN + relu + row L2-normalize, C=512, in place ------------
__global__ __launch_bounds__(256)
void apply_norm512(short* __restrict__ Y, const float* __restrict__ stats)
{
    int w = threadIdx.x >> 6, l = threadIdx.x & 63;
    long row = (long)blockIdx.x * 4 + w;
    short8 yv = *(const short8*)(Y + row * 512 + l * 8);
    float v[8];
    float ss = 0.f;
#pragma unroll
    for (int i = 0; i < 8; i++) {
        int c = l * 8 + i;
        float t = fmaxf(bf2f(yv[i]) * stats[c] + stats[512 + c], 0.f);
        v[i] = t;
        ss += t * t;
    }
#pragma unroll
    for (int off = 1; off < 64; off <<= 1) ss += __shfl_xor(ss, off, 64);
    float scl = 1.f / fmaxf(sqrtf(ss), 1e-12f);
    short8 o;
#pragma unroll
    for (int i = 0; i < 8; i++) o[i] = f2bf(v[i] * scl);
    *(short8*)(Y + row * 512 + l * 8) = o;
}

// ---------------- attention: per (s, 64 a-rows) block, XCD-swizzled --------
__global__ __launch_bounds__(256)
void attention(const short* __restrict__ q, const short* __restrict__ k,
               const short* __restrict__ v, const int* __restrict__ b_lens,
               short* __restrict__ wv, int wvStride)
{
    __shared__ short tile[32 * 520];
    __shared__ short Pscr[4][16 * 40];
    const int lin = blockIdx.x;
    const int xcd = lin & 7, sl = lin >> 3;
    const int a0 = (sl & 1) * 64;
    const int s = (sl >> 1) * 8 + xcd;
    const int tid = threadIdx.x;
    const int w = tid >> 6, l = tid & 63;
    const int quad = l >> 4, l15 = l & 15;
    const int blen = b_lens[s];
    const int sr = tid >> 3;
    const int scg = (tid & 7) * 8;

    short8 qf[16];
    const short* qbase = q + ((long)(s * 128 + a0 + w * 16 + l15)) * 512 + quad * 8;
#pragma unroll
    for (int kk = 0; kk < 16; kk++) qf[kk] = *(const short8*)(qbase + kk * 32);

    floatx4 sc[32];
#pragma unroll
    for (int i = 0; i < 32; i++) sc[i] = (floatx4){0.f, 0.f, 0.f, 0.f};

    const short* kbase = k + (long)s * 512 * 512;
    for (int bt2 = 0; bt2 < 16; ++bt2) {
        __syncthreads();
        const short* krow = kbase + (long)(bt2 * 32 + sr) * 512;
#pragma unroll
        for (int i = 0; i < 2; i++) {
            short8 t0 = *(const short8*)(krow + i * 256 + scg);
            short8 t1 = *(const short8*)(krow + i * 256 + 64 + scg);
            short8 t2 = *(const short8*)(krow + i * 256 + 128 + scg);
            short8 t3 = *(const short8*)(krow + i * 256 + 192 + scg);
            *(short8*)(&tile[sr * 520 + i * 256 + scg]) = t0;
            *(short8*)(&tile[sr * 520 + i * 256 + 64 + scg]) = t1;
            *(short8*)(&tile[sr * 520 + i * 256 + 128 + scg]) = t2;
            *(short8*)(&tile[sr * 520 + i * 256 + 192 + scg]) = t3;
        }
        __syncthreads();
#pragma unroll
        for (int kk = 0; kk < 16; kk++) {
            short8 f0 = *(const short8*)(&tile[l15 * 520 + kk * 32 + quad * 8]);
            short8 f1 = *(const short8*)(&tile[(16 + l15) * 520 + kk * 32 + quad * 8]);
            sc[bt2 * 2]     = __builtin_amdgcn_mfma_f32_16x16x32_bf16(qf[kk], f0, sc[bt2 * 2], 0, 0, 0);
            sc[bt2 * 2 + 1] = __builtin_amdgcn_mfma_f32_16x16x32_bf16(qf[kk], f1, sc[bt2 * 2 + 1], 0, 0, 0);
        }
    }

    const float scaler = 6.25f;
    float mrow[4] = {-__builtin_inff(), -__builtin_inff(), -__builtin_inff(), -__builtin_inff()};
#pragma unroll
    for (int bt = 0; bt < 32; ++bt) {
        bool valid = (bt * 16 + l15) < blen;
#pragma unroll
        for (int r = 0; r < 4; r++) {
            float v2 = valid ? sc[bt][r] * scaler : -__builtin_inff();
            sc[bt][r] = v2;
            mrow[r] = fmaxf(mrow[r], v2);
        }
    }
#pragma unroll
    for (int r = 0; r < 4; r++) {
#pragma unroll
        for (int off = 1; off < 16; off <<= 1)
            mrow[r] = fmaxf(mrow[r], __shfl_xor(mrow[r], off, 64));
    }
    float ssum[4] = {0.f, 0.f, 0.f, 0.f};
#pragma unroll
    for (int bt = 0; bt < 32; ++bt)
#pragma unroll
        for (int r = 0; r < 4; r++) {
            float p = __expf(sc[bt][r] - mrow[r]);
            sc[bt][r] = p;
            ssum[r] += p;
        }
#pragma unroll
    for (int r = 0; r < 4; r++) {
#pragma unroll
        for (int off = 1; off < 16; off <<= 1) ssum[r] += __shfl_xor(ssum[r], off, 64);
        ssum[r] = 1.f / ssum[r];
    }

    short8 pf[16];
    short* Pw = Pscr[w];
#pragma unroll
    for (int kk = 0; kk < 16; kk++) {
#pragma unroll
        for (int half = 0; half < 2; half++)
#pragma unroll
            for (int r = 0; r < 4; r++)
                Pw[(quad * 4 + r) * 40 + half * 16 + l15] = f2bf(sc[kk * 2 + half][r] * ssum[r]);
        pf[kk] = *(const short8*)(&Pw[l15 * 40 + quad * 8]);
    }

    const short* vbase = v + (long)s * 512 * 512;
    short* wvbase = wv + (long)(s * 128 + a0 + w * 16 + quad * 4) * wvStride;
    for (int dt = 0; dt < 16; ++dt) {
        __syncthreads();
#pragma unroll
        for (int round = 0; round < 2; round++) {
            int b = round * 256 + tid;
            const short* vr = vbase + (long)b * 512 + dt * 32;
            short8 x0 = *(const short8*)(vr);
            short8 x1 = *(const short8*)(vr + 8);
            short8 x2 = *(const short8*)(vr + 16);
            short8 x3 = *(const short8*)(vr + 24);
#pragma unroll
            for (int j = 0; j < 8; j++) {
                tile[j * 520 + b]        = x0[j];
                tile[(8 + j) * 520 + b]  = x1[j];
                tile[(16 + j) * 520 + b] = x2[j];
                tile[(24 + j) * 520 + b] = x3[j];
            }
        }
        __syncthreads();
        floatx4 o0 = (floatx4){0.f, 0.f, 0.f, 0.f};
        floatx4 o1 = (floatx4){0.f, 0.f, 0.f, 0.f};
#pragma unroll
        for (int kk = 0; kk < 16; kk++) {
            short8 f0 = *(const short8*)(&tile[l15 * 520 + kk * 32 + quad * 8]);
            short8 f1 = *(const short8*)(&tile[(16 + l15) * 520 + kk * 32 + quad * 8]);
            o0 = __builtin_amdgcn_mfma_f32_16x16x32_bf16(pf[kk], f0, o0, 0, 0, 0);
            o1 = __builtin_amdgcn_mfma_f32_16x16x32_bf16(pf[kk], f1, o1, 0, 0, 0);
        }
#pragma unroll
        for (int r = 0; r < 4; r++) {
            wvbase[(long)r * wvStride + dt * 32 + l15]      = f2bf(o0[r]);
            wvbase[(long)r * wvStride + dt * 32 + 16 + l15] = f2bf(o1[r]);
        }
    }

    if (wvStride > 512) {
        int r = tid >> 2, cb = (tid & 3) * 16;
        short8 z = (short8){0, 0, 0, 0, 0, 0, 0, 0};
        short* pz = wv + (long)(s * 128 + a0 + r) * wvStride + 512 + cb;
        *(short8*)(pz) = z;
        *(short8*)(pz + 8) = z;
    }
}

// ---------------- f: BN + relu + mask_a -> d_out fp32 ----------------------
__global__ __launch_bounds__(256)
void apply_f(const short* __restrict__ Yf, const float* __restrict__ stats,
             const int* __restrict__ a_lens, float* __restrict__ out)
{
    const long total = (long)32768 * 256;
    for (long e = (long)blockIdx.x * 256 + threadIdx.x; e < total; e += (long)gridDim.x * 256) {
        int c = (int)(e & 255);
        long row = e >> 8;
        int sI = (int)(row >> 7), pos = (int)(row & 127);
        float v = fmaxf(bf2f(Yf[e]) * stats[c] + stats[256 + c], 0.f);
        out[e] = (pos < a_lens[sI]) ? v : 0.f;
    }
}

// ---------------------------------------------------------------------------
extern "C" void kernel_launch(void* const* d_in, const int* in_sizes, int n_in,
                              void* d_out, int out_size, void* d_ws, size_t ws_size,
                              hipStream_t stream)
{
    (void)in_sizes; (void)n_in; (void)out_size;
    const float* A     = (const float*)d_in[0];
    const float* B     = (const float*)d_in[1];
    const int* a_lens  = (const int*)d_in[2];
    const int* b_lens  = (const int*)d_in[3];
    const float* Wq    = (const float*)d_in[4];
    const float* bq    = (const float*)d_in[5];
    const float* gq    = (const float*)d_in[6];
    const float* betaq = (const float*)d_in[7];
    const float* Wk    = (const float*)d_in[8];
    const float* bk    = (const float*)d_in[9];
    const float* gk    = (const float*)d_in[10];
    const float* betak = (const float*)d_in[11];
    const float* Wv    = (const float*)d_in[12];
    const float* bv    = (const float*)d_in[13];
    const float* gv    = (const float*)d_in[14];
    const float* betav = (const float*)d_in[15];
    const float* Wf    = (const float*)d_in[16];
    const float* bfp   = (const float*)d_in[17];
    const float* gf    = (const float*)d_in[18];
    const float* betaf = (const float*)d_in[19];
    float* out = (float*)d_out;
    char* base = (char*)d_ws;

    const size_t oWqb = 0;
    const size_t oWkb = oWqb + 294912;
    const size_t oWvb = oWkb + 294912;
    const size_t oWfb = oWvb + 294912;
    const size_t oBbf = oWfb + 294912;
    const size_t oQb  = oBbf + 75497472;
    const size_t oYv  = oQb + 33554432;
    const size_t oKb  = oYv + 134217728;
    const size_t oSt  = oKb + 134217728;
    const size_t FAST_NEED = oSt + 16384;

    if (ws_size >= FAST_NEED) {
        short* Wqb = (short*)(base + oWqb);
        short* Wkb = (short*)(base + oWkb);
        short* Wvb = (short*)(base + oWvb);
        short* Wfb = (short*)(base + oWfb);
        short* Bbf = (short*)(base + oBbf);
        short* qb  = (short*)(base + oQb);
        short* Yv  = (short*)(base + oYv);
        short* kb  = (short*)(base + oKb);
        short* Abf = (short*)(base + oKb);
        short* wvb = (short*)(base + oBbf);
        short* Yf  = (short*)(base + oQb);
        float* stQ = (float*)(base + oSt);
        float* stK = stQ + 1024;
        float* stV = stQ + 2048;
        float* stF = stQ + 3072;

        hipMemsetAsync(stQ, 0, 16384, stream);

        cvt_pad<<<32768, 256, 0, stream>>>(A, Abf, 256, 288);
        cvt_pad<<<131072, 256, 0, stream>>>(B, Bbf, 265, 288);
        cvt_pad<<<512, 256, 0, stream>>>(Wq, Wqb, 256, 288);
        cvt_pad<<<512, 256, 0, stream>>>(Wk, Wkb, 265, 288);
        cvt_pad<<<512, 256, 0, stream>>>(Wv, Wvb, 265, 288);
        cvt_pad<<<256, 256, 0, stream>>>(Wf, Wfb, 512, 576);

        // q projection: 256 m-tiles x 4 n-blocks, swizzled
        gemm128<<<1024, 256, 0, stream>>>(
            Abf, Wqb, Wqb, bq, bq, qb, qb, stQ, stQ, 512, 288, a_lens, 7, 2, 0);
        // fused k+v: one block computes BOTH v and k panels (clobbers Abf)
        gemm128x2<<<4096, 256, 0, stream>>>(
            Bbf, Wvb, Wkb, bv, bk, Yv, kb, stV, stK, 512, 288, b_lens, 9, 2);

        finalize_stats<<<1, 512, 0, stream>>>(stV, gv, betav, b_lens, 512);
        finalize_stats<<<1, 512, 0, stream>>>(stK, gk, betak, b_lens, 512);
        finalize_stats<<<1, 512, 0, stream>>>(stQ, gq, betaq, a_lens, 512);
        apply_norm512<<<32768, 256, 0, stream>>>(Yv, stV);
        apply_norm512<<<32768, 256, 0, stream>>>(kb, stK);
        apply_norm512<<<8192, 256, 0, stream>>>(qb, stQ);

        attention<<<512, 256, 0, stream>>>(qb, kb, Yv, b_lens, wvb, 576);

        gemm128<<<512, 256, 0, stream>>>(
            wvb, Wfb, Wfb, bfp, bfp, Yf, Yf, stF, stF, 256, 576, a_lens, 7, 1, 0);
        finalize_stats<<<1, 512, 0, stream>>>(stF, gf, betaf, a_lens, 256);
        apply_f<<<8192, 256, 0, stream>>>(Yf, stF, a_lens, out);
        return;
    }

    // ---- fallback: R1-style path (known correct) ----
    short* qb  = (short*)(base);
    short* Yv  = (short*)(base + 33554432);
    short* kb  = (short*)(base + 33554432 + 134217728);
    short* wvb = (short*)(base + 33554432 + 2L * 134217728);
    float* stQ = (float*)(base + 2L * 33554432 + 2L * 134217728);
    float* stK = stQ + 1024;
    float* stV = stQ + 2048;
    float* stF = stQ + 3072;
    short* Yf  = qb;

    hipMemsetAsync(stQ, 0, 16384, stream);

    gemm_bt<false, true><<<dim3(256, 4), 256, 0, stream>>>(
        A, Wq, bq, qb, 512, 256, 256, stQ, a_lens, 7);
    gemm_bt<false, false><<<dim3(1024, 4), 256, 0, stream>>>(
        B, Wv, bv, Yv, 512, 265, 288, stV, b_lens, 9);
    finalize_stats<<<1, 512, 0, stream>>>(stV, gv, betav, b_lens, 512);
    apply_norm512<<<32768, 256, 0, stream>>>(Yv, stV);
    gemm_bt<false, false><<<dim3(1024, 4), 256, 0, stream>>>(
        B, Wk, bk, kb, 512, 265, 288, stK, b_lens, 9);
    finalize_stats<<<1, 512, 0, stream>>>(stK, gk, betak, b_lens, 512);
    apply_norm512<<<32768, 256, 0, stream>>>(kb, stK);
    finalize_stats<<<1, 512, 0, stream>>>(stQ, gq, betaq, a_lens, 512);
    apply_norm512<<<8192, 256, 0, stream>>>(qb, stQ);
    attention<<<512, 256, 0, stream>>>(qb, kb, Yv, b_lens, wvb, 512);
    gemm_bt<true, true><<<dim3(256, 2), 256, 0, stream>>>(
        wvb, Wf, bfp, Yf, 256, 512, 512, stF, a_lens, 7);
    finalize_stats<<<1, 512, 0, stream>>>(stF, gf, betaf, a_lens, 256);
    apply_f<<<8192, 256, 0, stream>>>(Yf, stF, a_lens, out);
}

// Round 6
// 817.369 us; speedup vs baseline: 1.0247x; 1.0247x over previous
//
#include <hip/hip_runtime.h>
#include <hip/hip_bf16.h>
#include <stdint.h>

// ---------------------------------------------------------------------------
// AttentionBlock fast path. Round 6: WORK REDUCTION via mask-aware skipping.
// - kv-gemm: m-tiles fully beyond b_len are dead (attention masks them with
//   P=exp(-inf)=0 exactly) -> block early-return (~37.5% of tiles).
// - attention: bound QK^T/V-staging/PV loops by nkt=ceil(blen/32); a-half
//   blocks fully beyond a_len write zero wv rows and return.
// - apply_norm512 on k/v: early-exit blocks fully beyond b_len.
// - cvt_pad on B: skip rows beyond ceil128(b_len) (never read by live tiles).
// Invariant: every value read downstream comes from a computed tile; all
// dead values are multiplied by exactly-zero P or masked by msk=0 (finite).
// ---------------------------------------------------------------------------

typedef __attribute__((ext_vector_type(8))) short short8;
typedef __attribute__((ext_vector_type(4))) float floatx4;

__device__ __forceinline__ float bf2f(short h) {
    union { unsigned u; float f; } c;
    c.u = ((unsigned)(unsigned short)h) << 16;
    return c.f;
}
__device__ __forceinline__ short f2bf(float f) {
    union { float f; unsigned u; } c;
    c.f = f;
    unsigned u = c.u + 0x7fffu + ((c.u >> 16) & 1u);  // RNE
    return (short)(u >> 16);
}

__device__ __forceinline__ void async_cp16(const short* g, short* l) {
    __builtin_amdgcn_global_load_lds(
        (const __attribute__((address_space(1))) unsigned int*)g,
        (__attribute__((address_space(3))) unsigned int*)l, 16, 0, 0);
}

__device__ __forceinline__ short8 cvt8load(const float* p) {
    float4 f0 = *(const float4*)(p);
    float4 f1 = *(const float4*)(p + 4);
    short8 r;
    r[0] = f2bf(f0.x); r[1] = f2bf(f0.y); r[2] = f2bf(f0.z); r[3] = f2bf(f0.w);
    r[4] = f2bf(f1.x); r[5] = f2bf(f1.y); r[6] = f2bf(f1.z); r[7] = f2bf(f1.w);
    return r;
}
__device__ __forceinline__ short8 cvt8guard(const float* row, int c0, int Kin) {
    short8 r;
#pragma unroll
    for (int j = 0; j < 8; j++) {
        int c = c0 + j;
        r[j] = (c < Kin) ? f2bf(row[c]) : (short)0;
    }
    return r;
}

// ---------------- convert fp32 -> bf16 with K padding ----------------------
__global__ __launch_bounds__(256) void cvt_pad(const float* __restrict__ in,
                                               short* __restrict__ out,
                                               int kin, int kout) {
    long row = blockIdx.x;
    const float* src = in + row * (long)kin;
    short* dst = out + row * (long)kout;
    for (int c = threadIdx.x; c < kout; c += 256)
        dst[c] = (c < kin) ? f2bf(src[c]) : (short)0;
}

// B variant: skip rows beyond ceil128(b_len) (never read by live kv tiles).
__global__ __launch_bounds__(256) void cvt_padB(const float* __restrict__ in,
                                                short* __restrict__ out,
                                                int kin, int kout,
                                                const int* __restrict__ lens) {
    long row = blockIdx.x;
    int pos = (int)(row & 511), s = (int)(row >> 9);
    if (pos >= ((lens[s] + 127) & ~127)) return;
    const float* src = in + row * (long)kin;
    short* dst = out + row * (long)kout;
    for (int c = threadIdx.x; c < kout; c += 256)
        dst[c] = (c < kin) ? f2bf(src[c]) : (short)0;
}

// ---------------- fused dual-output BT GEMM (kv): 128 x {Yv,Yk} x 128 ------
// Stage X-tile once, multiply against W0 and W1 panels. Counted vmcnt.
// NEW: early-return for m-tiles fully beyond b_len (output provably dead).
__global__ __launch_bounds__(256, 2)
void gemm128x2(const short* __restrict__ X,
               const short* __restrict__ W0, const short* __restrict__ W1,
               const float* __restrict__ bias0, const float* __restrict__ bias1,
               short* __restrict__ Y0, short* __restrict__ Y1,
               float* __restrict__ st0, float* __restrict__ st1,
               int N, int Kp, const int* __restrict__ lens, int Lshift,
               int nShift)
{
    __shared__ short SH[36864];   // 3 bufs x (At | B0 | B1) x 4096 sh
    const int lin = blockIdx.x;
    const int xcd = lin & 7, sl = lin >> 3;
    const int nb = sl & ((1 << nShift) - 1);
    const int ms = sl >> nShift;
    const int m0 = (ms * 8 + xcd) * 128;
    // dead-tile skip: all 128 rows beyond this s's b_len
    if ((m0 & ((1 << Lshift) - 1)) >= lens[m0 >> Lshift]) return;
    const int n0 = nb * 128;

    const int tid = threadIdx.x;
    const int l = tid & 63, w = tid >> 6;
    const int quad = l >> 4, l15 = l & 15;
    const int wr = w & 1, wc = w >> 1;
    const int mo = wr * 64, no = wc * 64;

    floatx4 acc0[4][4], acc1[4][4];
#pragma unroll
    for (int i = 0; i < 4; i++)
#pragma unroll
        for (int j = 0; j < 4; j++) {
            acc0[i][j] = (floatx4){0.f, 0.f, 0.f, 0.f};
            acc1[i][j] = (floatx4){0.f, 0.f, 0.f, 0.f};
        }

    // source pre-swizzle (inverse of read-swizzle S -> L = S^(((S>>6)&7)<<4))
    int srow[2], scolS[2];
#pragma unroll
    for (int c = 0; c < 2; c++) {
        int L = tid * 16 + c * 4096;
        int S = L ^ ((((L >> 6) ^ (L >> 8)) & 1) << 4)
                  ^ (((L >> 7) & 1) << 5)
                  ^ (((L >> 8) & 1) << 6);
        srow[c] = S >> 6;
        scolS[c] = (S & 48) >> 1;
    }
    const short* Xs[2];
    const short* W0s[2];
    const short* W1s[2];
#pragma unroll
    for (int c = 0; c < 2; c++) {
        Xs[c]  = X  + (long)(m0 + srow[c]) * Kp + scolS[c];
        W0s[c] = W0 + (long)(n0 + srow[c]) * Kp + scolS[c];
        W1s[c] = W1 + (long)(n0 + srow[c]) * Kp + scolS[c];
    }
    const int nsteps = Kp >> 5;

    int rsA[4], rsB[4];
#pragma unroll
    for (int i = 0; i < 4; i++) {
        int rA = mo + i * 16 + l15;
        int rB = no + i * 16 + l15;
        rsA[i] = (rA << 6) ^ ((rA & 7) << 4) ^ (quad << 4);
        rsB[i] = (rB << 6) ^ ((rB & 7) << 4) ^ (quad << 4);
    }

    auto stage = [&](int buf, int t) {
        short* At = SH + buf * 12288;
        short* B0t = At + 4096;
        short* B1t = At + 8192;
        const int ko = t * 32;
#pragma unroll
        for (int c = 0; c < 2; c++)
            async_cp16(Xs[c] + ko, At + c * 2048 + tid * 8);
#pragma unroll
        for (int c = 0; c < 2; c++)
            async_cp16(W0s[c] + ko, B0t + c * 2048 + tid * 8);
#pragma unroll
        for (int c = 0; c < 2; c++)
            async_cp16(W1s[c] + ko, B1t + c * 2048 + tid * 8);
    };

    stage(0, 0);
    if (nsteps > 1) stage(1, 1);
    if (nsteps > 2) stage(2, 2);

    int cur = 0;
    for (int t = 0; t < nsteps; t++) {
        if (t + 2 < nsteps)      asm volatile("s_waitcnt vmcnt(12)" ::: "memory");
        else if (t + 1 < nsteps) asm volatile("s_waitcnt vmcnt(6)" ::: "memory");
        else                     asm volatile("s_waitcnt vmcnt(0)" ::: "memory");
        __builtin_amdgcn_s_barrier();
        __builtin_amdgcn_sched_barrier(0);

        const char* At = (const char*)(SH + cur * 12288);
        const char* B0t = At + 8192;
        const char* B1t = At + 16384;
        short8 af[4], bfr[4];
#pragma unroll
        for (int i = 0; i < 4; i++)
            af[i] = *(const short8*)(At + rsA[i]);
#pragma unroll
        for (int j = 0; j < 4; j++)
            bfr[j] = *(const short8*)(B0t + rsB[j]);
#pragma unroll
        for (int i = 0; i < 4; i++)
#pragma unroll
            for (int j = 0; j < 4; j++)
                acc0[i][j] = __builtin_amdgcn_mfma_f32_16x16x32_bf16(af[i], bfr[j], acc0[i][j], 0, 0, 0);
#pragma unroll
        for (int j = 0; j < 4; j++)
            bfr[j] = *(const short8*)(B1t + rsB[j]);
#pragma unroll
        for (int i = 0; i < 4; i++)
#pragma unroll
            for (int j = 0; j < 4; j++)
                acc1[i][j] = __builtin_amdgcn_mfma_f32_16x16x32_bf16(af[i], bfr[j], acc1[i][j], 0, 0, 0);

        __builtin_amdgcn_sched_barrier(0);
        __builtin_amdgcn_s_barrier();
        if (t + 3 < nsteps) stage(cur, t + 3);
        cur = (cur == 2) ? 0 : cur + 1;
    }

    const int Lmask = (1 << Lshift) - 1;
    float msk[4][4];
#pragma unroll
    for (int i = 0; i < 4; i++)
#pragma unroll
        for (int r = 0; r < 4; r++) {
            int rg = m0 + mo + i * 16 + quad * 4 + r;
            msk[i][r] = ((rg & Lmask) < lens[rg >> Lshift]) ? 1.f : 0.f;
        }
    short* Cs = SH;

    auto epi = [&](floatx4 (&acc)[4][4], const float* bias, float* stats, short* Y) {
        float bv[4];
#pragma unroll
        for (int j = 0; j < 4; j++) bv[j] = bias[n0 + no + j * 16 + l15];
#pragma unroll
        for (int j = 0; j < 4; j++) {
            float ps = 0.f, pss = 0.f;
#pragma unroll
            for (int i = 0; i < 4; i++)
#pragma unroll
                for (int r = 0; r < 4; r++) {
                    float v = acc[i][j][r] + bv[j];
                    ps += v * msk[i][r];
                    pss += v * v * msk[i][r];
                }
            ps  += __shfl_xor(ps, 16, 64);  ps  += __shfl_xor(ps, 32, 64);
            pss += __shfl_xor(pss, 16, 64); pss += __shfl_xor(pss, 32, 64);
            if (l < 16) {
                atomicAdd(&stats[n0 + no + j * 16 + l15], ps);
                atomicAdd(&stats[N + n0 + no + j * 16 + l15], pss);
            }
        }
#pragma unroll
        for (int pass = 0; pass < 2; pass++) {
            __syncthreads();
            if (wr == pass) {
#pragma unroll
                for (int j = 0; j < 4; j++)
#pragma unroll
                    for (int i = 0; i < 4; i++)
#pragma unroll
                        for (int r = 0; r < 4; r++)
                            Cs[(i * 16 + quad * 4 + r) * 132 + no + j * 16 + l15] =
                                f2bf(acc[i][j][r] + bv[j]);
            }
            __syncthreads();
#pragma unroll
            for (int c = 0; c < 4; c++) {
                int e = c * 2048 + tid * 8;
                int row = e >> 7, col = e & 127;
                short8 vv = *(const short8*)(Cs + row * 132 + col);
                *(short8*)(Y + (long)(m0 + pass * 64 + row) * N + n0 + col) = vv;
            }
        }
    };
    epi(acc0, bias0, st0, Y0);
    epi(acc1, bias1, st1, Y1);
}

// ---------------- BT GEMM (counted vmcnt): q / f projections ---------------
__global__ __launch_bounds__(256, 3)
void gemm128(const short* __restrict__ X,
             const short* __restrict__ W0, const short* __restrict__ W1,
             const float* __restrict__ bias0, const float* __restrict__ bias1,
             short* __restrict__ Y0, short* __restrict__ Y1,
             float* __restrict__ st0, float* __restrict__ st1,
             int N, int Kp, const int* __restrict__ lens, int Lshift,
             int nShift, int dual)
{
    __shared__ short SH[24576];
    const int lin = blockIdx.x;
    const int xcd = lin & 7, sl = lin >> 3;
    const int nb = sl & ((1 << nShift) - 1);
    const int ms = sl >> nShift;
    const int m0 = (ms * 8 + xcd) * 128;
    int g = 0, n0;
    if (dual) { g = nb & 1; n0 = (nb >> 1) * 128; } else { n0 = nb * 128; }
    const short* W    = g ? W1 : W0;
    const float* bias = g ? bias1 : bias0;
    short* Y          = g ? Y1 : Y0;
    float* stats      = g ? st1 : st0;

    const int tid = threadIdx.x;
    const int l = tid & 63, w = tid >> 6;
    const int quad = l >> 4, l15 = l & 15;
    const int wr = w & 1, wc = w >> 1;
    const int mo = wr * 64, no = wc * 64;

    floatx4 acc[4][4];
#pragma unroll
    for (int i = 0; i < 4; i++)
#pragma unroll
        for (int j = 0; j < 4; j++) acc[i][j] = (floatx4){0.f, 0.f, 0.f, 0.f};

    const int srow = tid >> 2;
    const int scol = (tid & 3) * 8;
    const short* Xs = X + (long)(m0 + srow) * Kp + scol;
    const short* Ws = W + (long)(n0 + srow) * Kp + scol;
    const long strideR = (long)64 * Kp;
    const int nsteps = Kp >> 5;

    auto stage = [&](int buf, int t) {
        short* At = SH + buf * 8192;
        short* Bt = At + 4096;
        const short* Xk = Xs + t * 32;
        const short* Wk = Ws + t * 32;
        async_cp16(Xk,           At + tid * 8);
        async_cp16(Xk + strideR, At + 2048 + tid * 8);
        async_cp16(Wk,           Bt + tid * 8);
        async_cp16(Wk + strideR, Bt + 2048 + tid * 8);
    };

    stage(0, 0);
    if (nsteps > 1) stage(1, 1);
    if (nsteps > 2) stage(2, 2);

    int cur = 0;
    for (int t = 0; t < nsteps; t++) {
        if (t + 2 < nsteps)      asm volatile("s_waitcnt vmcnt(8)" ::: "memory");
        else if (t + 1 < nsteps) asm volatile("s_waitcnt vmcnt(4)" ::: "memory");
        else                     asm volatile("s_waitcnt vmcnt(0)" ::: "memory");
        __builtin_amdgcn_s_barrier();
        __builtin_amdgcn_sched_barrier(0);

        const short* At = SH + cur * 8192;
        const short* Bt = At + 4096;
        short8 af[4], bfr[4];
#pragma unroll
        for (int i = 0; i < 4; i++)
            af[i] = *(const short8*)(At + (mo + i * 16 + l15) * 32 + quad * 8);
#pragma unroll
        for (int j = 0; j < 4; j++)
            bfr[j] = *(const short8*)(Bt + (no + j * 16 + l15) * 32 + quad * 8);
#pragma unroll
        for (int i = 0; i < 4; i++)
#pragma unroll
            for (int j = 0; j < 4; j++)
                acc[i][j] = __builtin_amdgcn_mfma_f32_16x16x32_bf16(af[i], bfr[j], acc[i][j], 0, 0, 0);

        __builtin_amdgcn_sched_barrier(0);
        __builtin_amdgcn_s_barrier();
        if (t + 3 < nsteps) stage(cur, t + 3);
        cur = (cur == 2) ? 0 : cur + 1;
    }

    const int Lmask = (1 << Lshift) - 1;
    float msk[4][4];
#pragma unroll
    for (int i = 0; i < 4; i++)
#pragma unroll
        for (int r = 0; r < 4; r++) {
            int rg = m0 + mo + i * 16 + quad * 4 + r;
            msk[i][r] = ((rg & Lmask) < lens[rg >> Lshift]) ? 1.f : 0.f;
        }
    float bv[4];
#pragma unroll
    for (int j = 0; j < 4; j++) bv[j] = bias[n0 + no + j * 16 + l15];

#pragma unroll
    for (int j = 0; j < 4; j++) {
        float ps = 0.f, pss = 0.f;
#pragma unroll
        for (int i = 0; i < 4; i++)
#pragma unroll
            for (int r = 0; r < 4; r++) {
                float v = acc[i][j][r] + bv[j];
                ps += v * msk[i][r];
                pss += v * v * msk[i][r];
            }
        ps  += __shfl_xor(ps, 16, 64);  ps  += __shfl_xor(ps, 32, 64);
        pss += __shfl_xor(pss, 16, 64); pss += __shfl_xor(pss, 32, 64);
        if (l < 16) {
            atomicAdd(&stats[n0 + no + j * 16 + l15], ps);
            atomicAdd(&stats[N + n0 + no + j * 16 + l15], pss);
        }
    }

    short* Cs = SH;
#pragma unroll
    for (int pass = 0; pass < 2; pass++) {
        __syncthreads();
        if (wr == pass) {
#pragma unroll
            for (int j = 0; j < 4; j++)
#pragma unroll
                for (int i = 0; i < 4; i++)
#pragma unroll
                    for (int r = 0; r < 4; r++)
                        Cs[(i * 16 + quad * 4 + r) * 132 + no + j * 16 + l15] =
                            f2bf(acc[i][j][r] + bv[j]);
        }
        __syncthreads();
#pragma unroll
        for (int c = 0; c < 4; c++) {
            int e = c * 2048 + tid * 8;
            int row = e >> 7, col = e & 127;
            short8 vv = *(const short8*)(Cs + row * 132 + col);
            *(short8*)(Y + (long)(m0 + pass * 64 + row) * N + n0 + col) = vv;
        }
    }
}

// ---------------- fallback BT GEMM (R1: fused fp32 cvt staging) ------------
template<bool XBF16, bool KAL>
__global__ __launch_bounds__(256, 2)
void gemm_bt(const void* __restrict__ Xp, const float* __restrict__ W,
             const float* __restrict__ bias, short* __restrict__ Y,
             int N, int Kin, int Kp, float* __restrict__ stats,
             const int* __restrict__ lens, int Lshift)
{
    __shared__ short At[128 * 32];
    __shared__ short Bt[128 * 32];
    const int m0 = blockIdx.x * 128;
    const int n0 = blockIdx.y * 128;
    const int tid = threadIdx.x;
    const int w = tid >> 6, l = tid & 63;
    const int quad = l >> 4, l15 = l & 15;
    const int mo = (w & 1) * 64, no = (w >> 1) * 64;

    floatx4 acc[4][4];
#pragma unroll
    for (int i = 0; i < 4; i++)
#pragma unroll
        for (int j = 0; j < 4; j++) acc[i][j] = (floatx4){0.f, 0.f, 0.f, 0.f};

    const int srow = tid >> 2;
    const int sc8 = (tid & 3) * 8;

    for (int k0 = 0; k0 < Kp; k0 += 32) {
        __syncthreads();
        const int c0 = k0 + sc8;
        short8 a0, a1, b0, b1;
        if (XBF16) {
            const short* X = (const short*)Xp;
            a0 = *(const short8*)(X + (long)(m0 + srow) * Kp + c0);
            a1 = *(const short8*)(X + (long)(m0 + 64 + srow) * Kp + c0);
        } else {
            const float* X = (const float*)Xp;
            if (KAL) {
                a0 = cvt8load(X + (long)(m0 + srow) * Kin + c0);
                a1 = cvt8load(X + (long)(m0 + 64 + srow) * Kin + c0);
            } else {
                a0 = cvt8guard(X + (long)(m0 + srow) * Kin, c0, Kin);
                a1 = cvt8guard(X + (long)(m0 + 64 + srow) * Kin, c0, Kin);
            }
        }
        if (KAL) {
            b0 = cvt8load(W + (long)(n0 + srow) * Kin + c0);
            b1 = cvt8load(W + (long)(n0 + 64 + srow) * Kin + c0);
        } else {
            b0 = cvt8guard(W + (long)(n0 + srow) * Kin, c0, Kin);
            b1 = cvt8guard(W + (long)(n0 + 64 + srow) * Kin, c0, Kin);
        }
        *(short8*)(At + srow * 32 + sc8) = a0;
        *(short8*)(At + (64 + srow) * 32 + sc8) = a1;
        *(short8*)(Bt + srow * 32 + sc8) = b0;
        *(short8*)(Bt + (64 + srow) * 32 + sc8) = b1;
        __syncthreads();
        short8 af[4], bfr[4];
#pragma unroll
        for (int i = 0; i < 4; i++) {
            af[i]  = *(const short8*)(At + (mo + i * 16 + l15) * 32 + quad * 8);
            bfr[i] = *(const short8*)(Bt + (no + i * 16 + l15) * 32 + quad * 8);
        }
#pragma unroll
        for (int i = 0; i < 4; i++)
#pragma unroll
            for (int j = 0; j < 4; j++)
                acc[i][j] = __builtin_amdgcn_mfma_f32_16x16x32_bf16(af[i], bfr[j], acc[i][j], 0, 0, 0);
    }

    const int Lmask = (1 << Lshift) - 1;
    float msk[4][4];
#pragma unroll
    for (int i = 0; i < 4; i++)
#pragma unroll
        for (int r = 0; r < 4; r++) {
            int rg = m0 + mo + i * 16 + quad * 4 + r;
            msk[i][r] = ((rg & Lmask) < lens[rg >> Lshift]) ? 1.f : 0.f;
        }
#pragma unroll
    for (int j = 0; j < 4; j++) {
        int colj = n0 + no + j * 16 + l15;
        float bvs = bias[colj];
        float ps = 0.f, pss = 0.f;
#pragma unroll
        for (int i = 0; i < 4; i++)
#pragma unroll
            for (int r = 0; r < 4; r++) {
                int rg = m0 + mo + i * 16 + quad * 4 + r;
                float v = acc[i][j][r] + bvs;
                Y[(long)rg * N + colj] = f2bf(v);
                ps += v * msk[i][r];
                pss += v * v * msk[i][r];
            }
        ps  += __shfl_xor(ps, 16, 64);  ps  += __shfl_xor(ps, 32, 64);
        pss += __shfl_xor(pss, 16, 64); pss += __shfl_xor(pss, 32, 64);
        if (l < 16) {
            atomicAdd(&stats[colj], ps);
            atomicAdd(&stats[N + colj], pss);
        }
    }
}

// ---------------- finalize: stats -> {scale, shift} per channel ------------
__global__ void finalize_stats(float* __restrict__ stats, const float* __restrict__ g,
                               const float* __restrict__ beta,
                               const int* __restrict__ lens, int C)
{
    __shared__ int lred[256];
    int t = threadIdx.x;
    if (t < 256) lred[t] = lens[t];
    __syncthreads();
    for (int s2 = 128; s2 > 0; s2 >>= 1) {
        if (t < s2) lred[t] += lred[t + s2];
        __syncthreads();
    }
    float cnt = (float)lred[0];
    if (t < C) {
        float mean = stats[t] / cnt;
        float var = fmaxf(stats[C + t] / cnt - mean * mean, 0.f);
        float a = rsqrtf(var + 1e-5f) * g[t];
        stats[t] = a;
        stats[C + t] = beta[t] - mean * a;
    }
}

// ---------------- BN + relu + row L2-normalize, C=512, in place ------------
__global__ __launch_bounds__(256)
void apply_norm512(short* __restrict__ Y, const float* __restrict__ stats)
{
    int w = threadIdx.x >> 6, l = threadIdx.x & 63;
    long row = (long)blockIdx.x * 4 + w;
    short8 yv = *(const short8*)(Y + row * 512 + l * 8);
    float v[8];
    float ss = 0.f;
#pragma unroll
    for (int i = 0; i < 8; i++) {
        int c = l * 8 + i;
        float t = fmaxf(bf2f(yv[i]) * stats[c] + stats[512 + c], 0.f);
        v[i] = t;
        ss += t * t;
    }
#pragma unroll
    for (int off = 1; off < 64; off <<= 1) ss += __shfl_xor(ss, off, 64);
    float scl = 1.f / fmaxf(sqrtf(ss), 1e-12f);
    short8 o;
#pragma unroll
    for (int i = 0; i < 8; i++) o[i] = f2bf(v[i] * scl);
    *(short8*)(Y + row * 512 + l * 8) = o;
}

// k/v variant: early-exit blocks whose 4 rows are all beyond b_len (dead).
__global__ __launch_bounds__(256)
void apply_norm512_len(short* __restrict__ Y, const float* __restrict__ stats,
                       const int* __restrict__ lens)
{
    int bid = blockIdx.x;
    if (((bid & 127) * 4) >= lens[bid >> 7]) return;
    int w = threadIdx.x >> 6, l = threadIdx.x & 63;
    long row = (long)bid * 4 + w;
    short8 yv = *(const short8*)(Y + row * 512 + l * 8);
    float v[8];
    float ss = 0.f;
#pragma unroll
    for (int i = 0; i < 8; i++) {
        int c = l * 8 + i;
        float t = fmaxf(bf2f(yv[i]) * stats[c] + stats[512 + c], 0.f);
        v[i] = t;
        ss += t * t;
    }
#pragma unroll
    for (int off = 1; off < 64; off <<= 1) ss += __shfl_xor(ss, off, 64);
    float scl = 1.f / fmaxf(sqrtf(ss), 1e-12f);
    short8 o;
#pragma unroll
    for (int i = 0; i < 8; i++) o[i] = f2bf(v[i] * scl);
    *(short8*)(Y + row * 512 + l * 8) = o;
}

// ---------------- attention: per (s, 64 a-rows) block, XCD-swizzled --------
// Bounded by nkt = ceil(blen/32): QK^T staging+MFMA, V staging, PV loops.
// a-half blocks fully beyond a_len write zero wv rows and return (keeps
// f-gemm inputs finite; those rows are msk=0 in f stats and masked in out).
__global__ __launch_bounds__(256)
void attention(const short* __restrict__ q, const short* __restrict__ k,
               const short* __restrict__ v, const int* __restrict__ b_lens,
               const int* __restrict__ a_lens,
               short* __restrict__ wv, int wvStride)
{
    __shared__ short tile[32 * 520];
    __shared__ short Pscr[4][16 * 40];
    const int lin = blockIdx.x;
    const int xcd = lin & 7, sl = lin >> 3;
    const int a0 = (sl & 1) * 64;
    const int s = (sl >> 1) * 8 + xcd;
    const int tid = threadIdx.x;
    const int w = tid >> 6, l = tid & 63;
    const int quad = l >> 4, l15 = l & 15;
    const int blen = b_lens[s];

    // dead a-half: zero-fill wv rows (finite for f-gemm) and exit
    if (a_lens[s] <= a0) {
        short8 z = (short8){0, 0, 0, 0, 0, 0, 0, 0};
        short* wz = wv + (long)(s * 128 + a0) * wvStride;
        const int total = 64 * wvStride;
        for (int e = tid * 8; e < total; e += 2048)
            *(short8*)(wz + e) = z;
        return;
    }

    const int nkt = (blen + 31) >> 5;   // live 32-row k/v tiles: 1..16
    const int sr = tid >> 3;
    const int scg = (tid & 7) * 8;

    short8 qf[16];
    const short* qbase = q + ((long)(s * 128 + a0 + w * 16 + l15)) * 512 + quad * 8;
#pragma unroll
    for (int kk = 0; kk < 16; kk++) qf[kk] = *(const short8*)(qbase + kk * 32);

    floatx4 sc[32];
#pragma unroll
    for (int i = 0; i < 32; i++) sc[i] = (floatx4){0.f, 0.f, 0.f, 0.f};

    const short* kbase = k + (long)s * 512 * 512;
    for (int bt2 = 0; bt2 < nkt; ++bt2) {
        __syncthreads();
        const short* krow = kbase + (long)(bt2 * 32 + sr) * 512;
#pragma unroll
        for (int i = 0; i < 2; i++) {
            short8 t0 = *(const short8*)(krow + i * 256 + scg);
            short8 t1 = *(const short8*)(krow + i * 256 + 64 + scg);
            short8 t2 = *(const short8*)(krow + i * 256 + 128 + scg);
            short8 t3 = *(const short8*)(krow + i * 256 + 192 + scg);
            *(short8*)(&tile[sr * 520 + i * 256 + scg]) = t0;
            *(short8*)(&tile[sr * 520 + i * 256 + 64 + scg]) = t1;
            *(short8*)(&tile[sr * 520 + i * 256 + 128 + scg]) = t2;
            *(short8*)(&tile[sr * 520 + i * 256 + 192 + scg]) = t3;
        }
        __syncthreads();
#pragma unroll
        for (int kk = 0; kk < 16; kk++) {
            short8 f0 = *(const short8*)(&tile[l15 * 520 + kk * 32 + quad * 8]);
            short8 f1 = *(const short8*)(&tile[(16 + l15) * 520 + kk * 32 + quad * 8]);
            sc[bt2 * 2]     = __builtin_amdgcn_mfma_f32_16x16x32_bf16(qf[kk], f0, sc[bt2 * 2], 0, 0, 0);
            sc[bt2 * 2 + 1] = __builtin_amdgcn_mfma_f32_16x16x32_bf16(qf[kk], f1, sc[bt2 * 2 + 1], 0, 0, 0);
        }
    }

    const float scaler = 6.25f;
    float mrow[4] = {-__builtin_inff(), -__builtin_inff(), -__builtin_inff(), -__builtin_inff()};
#pragma unroll
    for (int bt = 0; bt < 32; ++bt) {
        bool valid = (bt * 16 + l15) < blen;
#pragma unroll
        for (int r = 0; r < 4; r++) {
            float v2 = valid ? sc[bt][r] * scaler : -__builtin_inff();
            sc[bt][r] = v2;
            mrow[r] = fmaxf(mrow[r], v2);
        }
    }
#pragma unroll
    for (int r = 0; r < 4; r++) {
#pragma unroll
        for (int off = 1; off < 16; off <<= 1)
            mrow[r] = fmaxf(mrow[r], __shfl_xor(mrow[r], off, 64));
    }
    float ssum[4] = {0.f, 0.f, 0.f, 0.f};
#pragma unroll
    for (int bt = 0; bt < 32; ++bt)
#pragma unroll
        for (int r = 0; r < 4; r++) {
            float p = __expf(sc[bt][r] - mrow[r]);
            sc[bt][r] = p;
            ssum[r] += p;
        }
#pragma unroll
    for (int r = 0; r < 4; r++) {
#pragma unroll
        for (int off = 1; off < 16; off <<= 1) ssum[r] += __shfl_xor(ssum[r], off, 64);
        ssum[r] = 1.f / ssum[r];
    }

    short8 pf[16];
    short* Pw = Pscr[w];
    for (int kk = 0; kk < nkt; kk++) {
#pragma unroll
        for (int half = 0; half < 2; half++)
#pragma unroll
            for (int r = 0; r < 4; r++)
                Pw[(quad * 4 + r) * 40 + half * 16 + l15] = f2bf(sc[kk * 2 + half][r] * ssum[r]);
        pf[kk] = *(const short8*)(&Pw[l15 * 40 + quad * 8]);
    }

    // phase 2: wv[a][d] = sum_{b<nkt*32} P[a][b] v[b][d] (P=0 beyond blen)
    const int nb32 = nkt * 32;
    const short* vbase = v + (long)s * 512 * 512;
    short* wvbase = wv + (long)(s * 128 + a0 + w * 16 + quad * 4) * wvStride;
    for (int dt = 0; dt < 16; ++dt) {
        __syncthreads();
#pragma unroll
        for (int round = 0; round < 2; round++) {
            int b = round * 256 + tid;
            if (b < nb32) {
                const short* vr = vbase + (long)b * 512 + dt * 32;
                short8 x0 = *(const short8*)(vr);
                short8 x1 = *(const short8*)(vr + 8);
                short8 x2 = *(const short8*)(vr + 16);
                short8 x3 = *(const short8*)(vr + 24);
#pragma unroll
                for (int j = 0; j < 8; j++) {
                    tile[j * 520 + b]        = x0[j];
                    tile[(8 + j) * 520 + b]  = x1[j];
                    tile[(16 + j) * 520 + b] = x2[j];
                    tile[(24 + j) * 520 + b] = x3[j];
                }
            }
        }
        __syncthreads();
        floatx4 o0 = (floatx4){0.f, 0.f, 0.f, 0.f};
        floatx4 o1 = (floatx4){0.f, 0.f, 0.f, 0.f};
        for (int kk = 0; kk < nkt; kk++) {
            short8 f0 = *(const short8*)(&tile[l15 * 520 + kk * 32 + quad * 8]);
            short8 f1 = *(const short8*)(&tile[(16 + l15) * 520 + kk * 32 + quad * 8]);
            o0 = __builtin_amdgcn_mfma_f32_16x16x32_bf16(pf[kk], f0, o0, 0, 0, 0);
            o1 = __builtin_amdgcn_mfma_f32_16x16x32_bf16(pf[kk], f1, o1, 0, 0, 0);
        }
#pragma unroll
        for (int r = 0; r < 4; r++) {
            wvbase[(long)r * wvStride + dt * 32 + l15]      = f2bf(o0[r]);
            wvbase[(long)r * wvStride + dt * 32 + 16 + l15] = f2bf(o1[r]);
        }
    }

    if (wvStride > 512) {
        int r = tid >> 2, cb = (tid & 3) * 16;
        short8 z = (short8){0, 0, 0, 0, 0, 0, 0, 0};
        short* pz = wv + (long)(s * 128 + a0 + r) * wvStride + 512 + cb;
        *(short8*)(pz) = z;
        *(short8*)(pz + 8) = z;
    }
}

// ---------------- f: BN + relu + mask_a -> d_out fp32 ----------------------
__global__ __launch_bounds__(256)
void apply_f(const short* __restrict__ Yf, const float* __restrict__ stats,
             const int* __restrict__ a_lens, float* __restrict__ out)
{
    const long total = (long)32768 * 256;
    for (long e = (long)blockIdx.x * 256 + threadIdx.x; e < total; e += (long)gridDim.x * 256) {
        int c = (int)(e & 255);
        long row = e >> 8;
        int sI = (int)(row >> 7), pos = (int)(row & 127);
        float v = fmaxf(bf2f(Yf[e]) * stats[c] + stats[256 + c], 0.f);
        out[e] = (pos < a_lens[sI]) ? v : 0.f;
    }
}

// ---------------------------------------------------------------------------
extern "C" void kernel_launch(void* const* d_in, const int* in_sizes, int n_in,
                              void* d_out, int out_size, void* d_ws, size_t ws_size,
                              hipStream_t stream)
{
    (void)in_sizes; (void)n_in; (void)out_size;
    const float* A     = (const float*)d_in[0];
    const float* B     = (const float*)d_in[1];
    const int* a_lens  = (const int*)d_in[2];
    const int* b_lens  = (const int*)d_in[3];
    const float* Wq    = (const float*)d_in[4];
    const float* bq    = (const float*)d_in[5];
    const float* gq    = (const float*)d_in[6];
    const float* betaq = (const float*)d_in[7];
    const float* Wk    = (const float*)d_in[8];
    const float* bk    = (const float*)d_in[9];
    const float* gk    = (const float*)d_in[10];
    const float* betak = (const float*)d_in[11];
    const float* Wv    = (const float*)d_in[12];
    const float* bv    = (const float*)d_in[13];
    const float* gv    = (const float*)d_in[14];
    const float* betav = (const float*)d_in[15];
    const float* Wf    = (const float*)d_in[16];
    const float* bfp   = (const float*)d_in[17];
    const float* gf    = (const float*)d_in[18];
    const float* betaf = (const float*)d_in[19];
    float* out = (float*)d_out;
    char* base = (char*)d_ws;

    const size_t oWqb = 0;
    const size_t oWkb = oWqb + 294912;
    const size_t oWvb = oWkb + 294912;
    const size_t oWfb = oWvb + 294912;
    const size_t oBbf = oWfb + 294912;
    const size_t oQb  = oBbf + 75497472;
    const size_t oYv  = oQb + 33554432;
    const size_t oKb  = oYv + 134217728;
    const size_t oSt  = oKb + 134217728;
    const size_t FAST_NEED = oSt + 16384;

    if (ws_size >= FAST_NEED) {
        short* Wqb = (short*)(base + oWqb);
        short* Wkb = (short*)(base + oWkb);
        short* Wvb = (short*)(base + oWvb);
        short* Wfb = (short*)(base + oWfb);
        short* Bbf = (short*)(base + oBbf);
        short* qb  = (short*)(base + oQb);
        short* Yv  = (short*)(base + oYv);
        short* kb  = (short*)(base + oKb);
        short* Abf = (short*)(base + oKb);
        short* wvb = (short*)(base + oBbf);
        short* Yf  = (short*)(base + oQb);
        float* stQ = (float*)(base + oSt);
        float* stK = stQ + 1024;
        float* stV = stQ + 2048;
        float* stF = stQ + 3072;

        hipMemsetAsync(stQ, 0, 16384, stream);

        cvt_pad<<<32768, 256, 0, stream>>>(A, Abf, 256, 288);
        cvt_padB<<<131072, 256, 0, stream>>>(B, Bbf, 265, 288, b_lens);
        cvt_pad<<<512, 256, 0, stream>>>(Wq, Wqb, 256, 288);
        cvt_pad<<<512, 256, 0, stream>>>(Wk, Wkb, 265, 288);
        cvt_pad<<<512, 256, 0, stream>>>(Wv, Wvb, 265, 288);
        cvt_pad<<<256, 256, 0, stream>>>(Wf, Wfb, 512, 576);

        // q projection: 256 m-tiles x 4 n-blocks, swizzled
        gemm128<<<1024, 256, 0, stream>>>(
            Abf, Wqb, Wqb, bq, bq, qb, qb, stQ, stQ, 512, 288, a_lens, 7, 2, 0);
        // fused k+v with dead-tile skip (clobbers Abf)
        gemm128x2<<<4096, 256, 0, stream>>>(
            Bbf, Wvb, Wkb, bv, bk, Yv, kb, stV, stK, 512, 288, b_lens, 9, 2);

        finalize_stats<<<1, 512, 0, stream>>>(stV, gv, betav, b_lens, 512);
        finalize_stats<<<1, 512, 0, stream>>>(stK, gk, betak, b_lens, 512);
        finalize_stats<<<1, 512, 0, stream>>>(stQ, gq, betaq, a_lens, 512);
        apply_norm512_len<<<32768, 256, 0, stream>>>(Yv, stV, b_lens);
        apply_norm512_len<<<32768, 256, 0, stream>>>(kb, stK, b_lens);
        apply_norm512<<<8192, 256, 0, stream>>>(qb, stQ);

        attention<<<512, 256, 0, stream>>>(qb, kb, Yv, b_lens, a_lens, wvb, 576);

        gemm128<<<512, 256, 0, stream>>>(
            wvb, Wfb, Wfb, bfp, bfp, Yf, Yf, stF, stF, 256, 576, a_lens, 7, 1, 0);
        finalize_stats<<<1, 512, 0, stream>>>(stF, gf, betaf, a_lens, 256);
        apply_f<<<8192, 256, 0, stream>>>(Yf, stF, a_lens, out);
        return;
    }

    // ---- fallback: R1-style path (known correct) ----
    short* qb  = (short*)(base);
    short* Yv  = (short*)(base + 33554432);
    short* kb  = (short*)(base + 33554432 + 134217728);
    short* wvb = (short*)(base + 33554432 + 2L * 134217728);
    float* stQ = (float*)(base + 2L * 33554432 + 2L * 134217728);
    float* stK = stQ + 1024;
    float* stV = stQ + 2048;
    float* stF = stQ + 3072;
    short* Yf  = qb;

    hipMemsetAsync(stQ, 0, 16384, stream);

    gemm_bt<false, true><<<dim3(256, 4), 256, 0, stream>>>(
        A, Wq, bq, qb, 512, 256, 256, stQ, a_lens, 7);
    gemm_bt<false, false><<<dim3(1024, 4), 256, 0, stream>>>(
        B, Wv, bv, Yv, 512, 265, 288, stV, b_lens, 9);
    finalize_stats<<<1, 512, 0, stream>>>(stV, gv, betav, b_lens, 512);
    apply_norm512<<<32768, 256, 0, stream>>>(Yv, stV);
    gemm_bt<false, false><<<dim3(1024, 4), 256, 0, stream>>>(
        B, Wk, bk, kb, 512, 265, 288, stK, b_lens, 9);
    finalize_stats<<<1, 512, 0, stream>>>(stK, gk, betak, b_lens, 512);
    apply_norm512<<<32768, 256, 0, stream>>>(kb, stK);
    finalize_stats<<<1, 512, 0, stream>>>(stQ, gq, betaq, a_lens, 512);
    apply_norm512<<<8192, 256, 0, stream>>>(qb, stQ);
    attention<<<512, 256, 0, stream>>>(qb, kb, Yv, b_lens, a_lens, wvb, 512);
    gemm_bt<true, true><<<dim3(256, 2), 256, 0, stream>>>(
        wvb, Wf, bfp, Yf, 256, 512, 512, stF, a_lens, 7);
    finalize_stats<<<1, 512, 0, stream>>>(stF, gf, betaf, a_lens, 256);
    apply_f<<<8192, 256, 0, stream>>>(Yf, stF, a_lens, out);
}

// Round 7
// 712.396 us; speedup vs baseline: 1.1757x; 1.1474x over previous
//
#include <hip/hip_runtime.h>
#include <hip/hip_bf16.h>
#include <stdint.h>

// ---------------------------------------------------------------------------
// AttentionBlock fast path. Round 7: fix rule-#20 scratch spill in attention.
// Round 6 bounded attention loops by runtime nkt -> sc[]/pf[] runtime-indexed
// -> demoted to scratch (VGPR=60, 221MB scratch writes, MfmaUtil 2%). Fix:
// block-uniform dispatch to template bodies NT in {4,8,12,16} (= ceil128
// granularity); ALL register-array indices compile-time; sc sized [2*NT].
// Work reduction from round 6 kept: kv dead-tile skip, norm skip, cvt skip,
// dead-a-half zero-fill.
// ---------------------------------------------------------------------------

typedef __attribute__((ext_vector_type(8))) short short8;
typedef __attribute__((ext_vector_type(4))) float floatx4;

__device__ __forceinline__ float bf2f(short h) {
    union { unsigned u; float f; } c;
    c.u = ((unsigned)(unsigned short)h) << 16;
    return c.f;
}
__device__ __forceinline__ short f2bf(float f) {
    union { float f; unsigned u; } c;
    c.f = f;
    unsigned u = c.u + 0x7fffu + ((c.u >> 16) & 1u);  // RNE
    return (short)(u >> 16);
}

__device__ __forceinline__ void async_cp16(const short* g, short* l) {
    __builtin_amdgcn_global_load_lds(
        (const __attribute__((address_space(1))) unsigned int*)g,
        (__attribute__((address_space(3))) unsigned int*)l, 16, 0, 0);
}

__device__ __forceinline__ short8 cvt8load(const float* p) {
    float4 f0 = *(const float4*)(p);
    float4 f1 = *(const float4*)(p + 4);
    short8 r;
    r[0] = f2bf(f0.x); r[1] = f2bf(f0.y); r[2] = f2bf(f0.z); r[3] = f2bf(f0.w);
    r[4] = f2bf(f1.x); r[5] = f2bf(f1.y); r[6] = f2bf(f1.z); r[7] = f2bf(f1.w);
    return r;
}
__device__ __forceinline__ short8 cvt8guard(const float* row, int c0, int Kin) {
    short8 r;
#pragma unroll
    for (int j = 0; j < 8; j++) {
        int c = c0 + j;
        r[j] = (c < Kin) ? f2bf(row[c]) : (short)0;
    }
    return r;
}

// ---------------- convert fp32 -> bf16 with K padding ----------------------
__global__ __launch_bounds__(256) void cvt_pad(const float* __restrict__ in,
                                               short* __restrict__ out,
                                               int kin, int kout) {
    long row = blockIdx.x;
    const float* src = in + row * (long)kin;
    short* dst = out + row * (long)kout;
    for (int c = threadIdx.x; c < kout; c += 256)
        dst[c] = (c < kin) ? f2bf(src[c]) : (short)0;
}

// B variant: skip rows beyond ceil128(b_len) (never read by live kv tiles).
__global__ __launch_bounds__(256) void cvt_padB(const float* __restrict__ in,
                                                short* __restrict__ out,
                                                int kin, int kout,
                                                const int* __restrict__ lens) {
    long row = blockIdx.x;
    int pos = (int)(row & 511), s = (int)(row >> 9);
    if (pos >= ((lens[s] + 127) & ~127)) return;
    const float* src = in + row * (long)kin;
    short* dst = out + row * (long)kout;
    for (int c = threadIdx.x; c < kout; c += 256)
        dst[c] = (c < kin) ? f2bf(src[c]) : (short)0;
}

// ---------------- fused dual-output BT GEMM (kv): 128 x {Yv,Yk} x 128 ------
__global__ __launch_bounds__(256, 2)
void gemm128x2(const short* __restrict__ X,
               const short* __restrict__ W0, const short* __restrict__ W1,
               const float* __restrict__ bias0, const float* __restrict__ bias1,
               short* __restrict__ Y0, short* __restrict__ Y1,
               float* __restrict__ st0, float* __restrict__ st1,
               int N, int Kp, const int* __restrict__ lens, int Lshift,
               int nShift)
{
    __shared__ short SH[36864];   // 3 bufs x (At | B0 | B1) x 4096 sh
    const int lin = blockIdx.x;
    const int xcd = lin & 7, sl = lin >> 3;
    const int nb = sl & ((1 << nShift) - 1);
    const int ms = sl >> nShift;
    const int m0 = (ms * 8 + xcd) * 128;
    if ((m0 & ((1 << Lshift) - 1)) >= lens[m0 >> Lshift]) return;  // dead tile
    const int n0 = nb * 128;

    const int tid = threadIdx.x;
    const int l = tid & 63, w = tid >> 6;
    const int quad = l >> 4, l15 = l & 15;
    const int wr = w & 1, wc = w >> 1;
    const int mo = wr * 64, no = wc * 64;

    floatx4 acc0[4][4], acc1[4][4];
#pragma unroll
    for (int i = 0; i < 4; i++)
#pragma unroll
        for (int j = 0; j < 4; j++) {
            acc0[i][j] = (floatx4){0.f, 0.f, 0.f, 0.f};
            acc1[i][j] = (floatx4){0.f, 0.f, 0.f, 0.f};
        }

    int srow[2], scolS[2];
#pragma unroll
    for (int c = 0; c < 2; c++) {
        int L = tid * 16 + c * 4096;
        int S = L ^ ((((L >> 6) ^ (L >> 8)) & 1) << 4)
                  ^ (((L >> 7) & 1) << 5)
                  ^ (((L >> 8) & 1) << 6);
        srow[c] = S >> 6;
        scolS[c] = (S & 48) >> 1;
    }
    const short* Xs[2];
    const short* W0s[2];
    const short* W1s[2];
#pragma unroll
    for (int c = 0; c < 2; c++) {
        Xs[c]  = X  + (long)(m0 + srow[c]) * Kp + scolS[c];
        W0s[c] = W0 + (long)(n0 + srow[c]) * Kp + scolS[c];
        W1s[c] = W1 + (long)(n0 + srow[c]) * Kp + scolS[c];
    }
    const int nsteps = Kp >> 5;

    int rsA[4], rsB[4];
#pragma unroll
    for (int i = 0; i < 4; i++) {
        int rA = mo + i * 16 + l15;
        int rB = no + i * 16 + l15;
        rsA[i] = (rA << 6) ^ ((rA & 7) << 4) ^ (quad << 4);
        rsB[i] = (rB << 6) ^ ((rB & 7) << 4) ^ (quad << 4);
    }

    auto stage = [&](int buf, int t) {
        short* At = SH + buf * 12288;
        short* B0t = At + 4096;
        short* B1t = At + 8192;
        const int ko = t * 32;
#pragma unroll
        for (int c = 0; c < 2; c++)
            async_cp16(Xs[c] + ko, At + c * 2048 + tid * 8);
#pragma unroll
        for (int c = 0; c < 2; c++)
            async_cp16(W0s[c] + ko, B0t + c * 2048 + tid * 8);
#pragma unroll
        for (int c = 0; c < 2; c++)
            async_cp16(W1s[c] + ko, B1t + c * 2048 + tid * 8);
    };

    stage(0, 0);
    if (nsteps > 1) stage(1, 1);
    if (nsteps > 2) stage(2, 2);

    int cur = 0;
    for (int t = 0; t < nsteps; t++) {
        if (t + 2 < nsteps)      asm volatile("s_waitcnt vmcnt(12)" ::: "memory");
        else if (t + 1 < nsteps) asm volatile("s_waitcnt vmcnt(6)" ::: "memory");
        else                     asm volatile("s_waitcnt vmcnt(0)" ::: "memory");
        __builtin_amdgcn_s_barrier();
        __builtin_amdgcn_sched_barrier(0);

        const char* At = (const char*)(SH + cur * 12288);
        const char* B0t = At + 8192;
        const char* B1t = At + 16384;
        short8 af[4], bfr[4];
#pragma unroll
        for (int i = 0; i < 4; i++)
            af[i] = *(const short8*)(At + rsA[i]);
#pragma unroll
        for (int j = 0; j < 4; j++)
            bfr[j] = *(const short8*)(B0t + rsB[j]);
#pragma unroll
        for (int i = 0; i < 4; i++)
#pragma unroll
            for (int j = 0; j < 4; j++)
                acc0[i][j] = __builtin_amdgcn_mfma_f32_16x16x32_bf16(af[i], bfr[j], acc0[i][j], 0, 0, 0);
#pragma unroll
        for (int j = 0; j < 4; j++)
            bfr[j] = *(const short8*)(B1t + rsB[j]);
#pragma unroll
        for (int i = 0; i < 4; i++)
#pragma unroll
            for (int j = 0; j < 4; j++)
                acc1[i][j] = __builtin_amdgcn_mfma_f32_16x16x32_bf16(af[i], bfr[j], acc1[i][j], 0, 0, 0);

        __builtin_amdgcn_sched_barrier(0);
        __builtin_amdgcn_s_barrier();
        if (t + 3 < nsteps) stage(cur, t + 3);
        cur = (cur == 2) ? 0 : cur + 1;
    }

    const int Lmask = (1 << Lshift) - 1;
    float msk[4][4];
#pragma unroll
    for (int i = 0; i < 4; i++)
#pragma unroll
        for (int r = 0; r < 4; r++) {
            int rg = m0 + mo + i * 16 + quad * 4 + r;
            msk[i][r] = ((rg & Lmask) < lens[rg >> Lshift]) ? 1.f : 0.f;
        }
    short* Cs = SH;

    auto epi = [&](floatx4 (&acc)[4][4], const float* bias, float* stats, short* Y) {
        float bv[4];
#pragma unroll
        for (int j = 0; j < 4; j++) bv[j] = bias[n0 + no + j * 16 + l15];
#pragma unroll
        for (int j = 0; j < 4; j++) {
            float ps = 0.f, pss = 0.f;
#pragma unroll
            for (int i = 0; i < 4; i++)
#pragma unroll
                for (int r = 0; r < 4; r++) {
                    float v = acc[i][j][r] + bv[j];
                    ps += v * msk[i][r];
                    pss += v * v * msk[i][r];
                }
            ps  += __shfl_xor(ps, 16, 64);  ps  += __shfl_xor(ps, 32, 64);
            pss += __shfl_xor(pss, 16, 64); pss += __shfl_xor(pss, 32, 64);
            if (l < 16) {
                atomicAdd(&stats[n0 + no + j * 16 + l15], ps);
                atomicAdd(&stats[N + n0 + no + j * 16 + l15], pss);
            }
        }
#pragma unroll
        for (int pass = 0; pass < 2; pass++) {
            __syncthreads();
            if (wr == pass) {
#pragma unroll
                for (int j = 0; j < 4; j++)
#pragma unroll
                    for (int i = 0; i < 4; i++)
#pragma unroll
                        for (int r = 0; r < 4; r++)
                            Cs[(i * 16 + quad * 4 + r) * 132 + no + j * 16 + l15] =
                                f2bf(acc[i][j][r] + bv[j]);
            }
            __syncthreads();
#pragma unroll
            for (int c = 0; c < 4; c++) {
                int e = c * 2048 + tid * 8;
                int row = e >> 7, col = e & 127;
                short8 vv = *(const short8*)(Cs + row * 132 + col);
                *(short8*)(Y + (long)(m0 + pass * 64 + row) * N + n0 + col) = vv;
            }
        }
    };
    epi(acc0, bias0, st0, Y0);
    epi(acc1, bias1, st1, Y1);
}

// ---------------- BT GEMM (counted vmcnt): q / f projections ---------------
__global__ __launch_bounds__(256, 3)
void gemm128(const short* __restrict__ X,
             const short* __restrict__ W0, const short* __restrict__ W1,
             const float* __restrict__ bias0, const float* __restrict__ bias1,
             short* __restrict__ Y0, short* __restrict__ Y1,
             float* __restrict__ st0, float* __restrict__ st1,
             int N, int Kp, const int* __restrict__ lens, int Lshift,
             int nShift, int dual)
{
    __shared__ short SH[24576];
    const int lin = blockIdx.x;
    const int xcd = lin & 7, sl = lin >> 3;
    const int nb = sl & ((1 << nShift) - 1);
    const int ms = sl >> nShift;
    const int m0 = (ms * 8 + xcd) * 128;
    int g = 0, n0;
    if (dual) { g = nb & 1; n0 = (nb >> 1) * 128; } else { n0 = nb * 128; }
    const short* W    = g ? W1 : W0;
    const float* bias = g ? bias1 : bias0;
    short* Y          = g ? Y1 : Y0;
    float* stats      = g ? st1 : st0;

    const int tid = threadIdx.x;
    const int l = tid & 63, w = tid >> 6;
    const int quad = l >> 4, l15 = l & 15;
    const int wr = w & 1, wc = w >> 1;
    const int mo = wr * 64, no = wc * 64;

    floatx4 acc[4][4];
#pragma unroll
    for (int i = 0; i < 4; i++)
#pragma unroll
        for (int j = 0; j < 4; j++) acc[i][j] = (floatx4){0.f, 0.f, 0.f, 0.f};

    const int srow = tid >> 2;
    const int scol = (tid & 3) * 8;
    const short* Xs = X + (long)(m0 + srow) * Kp + scol;
    const short* Ws = W + (long)(n0 + srow) * Kp + scol;
    const long strideR = (long)64 * Kp;
    const int nsteps = Kp >> 5;

    auto stage = [&](int buf, int t) {
        short* At = SH + buf * 8192;
        short* Bt = At + 4096;
        const short* Xk = Xs + t * 32;
        const short* Wk = Ws + t * 32;
        async_cp16(Xk,           At + tid * 8);
        async_cp16(Xk + strideR, At + 2048 + tid * 8);
        async_cp16(Wk,           Bt + tid * 8);
        async_cp16(Wk + strideR, Bt + 2048 + tid * 8);
    };

    stage(0, 0);
    if (nsteps > 1) stage(1, 1);
    if (nsteps > 2) stage(2, 2);

    int cur = 0;
    for (int t = 0; t < nsteps; t++) {
        if (t + 2 < nsteps)      asm volatile("s_waitcnt vmcnt(8)" ::: "memory");
        else if (t + 1 < nsteps) asm volatile("s_waitcnt vmcnt(4)" ::: "memory");
        else                     asm volatile("s_waitcnt vmcnt(0)" ::: "memory");
        __builtin_amdgcn_s_barrier();
        __builtin_amdgcn_sched_barrier(0);

        const short* At = SH + cur * 8192;
        const short* Bt = At + 4096;
        short8 af[4], bfr[4];
#pragma unroll
        for (int i = 0; i < 4; i++)
            af[i] = *(const short8*)(At + (mo + i * 16 + l15) * 32 + quad * 8);
#pragma unroll
        for (int j = 0; j < 4; j++)
            bfr[j] = *(const short8*)(Bt + (no + j * 16 + l15) * 32 + quad * 8);
#pragma unroll
        for (int i = 0; i < 4; i++)
#pragma unroll
            for (int j = 0; j < 4; j++)
                acc[i][j] = __builtin_amdgcn_mfma_f32_16x16x32_bf16(af[i], bfr[j], acc[i][j], 0, 0, 0);

        __builtin_amdgcn_sched_barrier(0);
        __builtin_amdgcn_s_barrier();
        if (t + 3 < nsteps) stage(cur, t + 3);
        cur = (cur == 2) ? 0 : cur + 1;
    }

    const int Lmask = (1 << Lshift) - 1;
    float msk[4][4];
#pragma unroll
    for (int i = 0; i < 4; i++)
#pragma unroll
        for (int r = 0; r < 4; r++) {
            int rg = m0 + mo + i * 16 + quad * 4 + r;
            msk[i][r] = ((rg & Lmask) < lens[rg >> Lshift]) ? 1.f : 0.f;
        }
    float bv[4];
#pragma unroll
    for (int j = 0; j < 4; j++) bv[j] = bias[n0 + no + j * 16 + l15];

#pragma unroll
    for (int j = 0; j < 4; j++) {
        float ps = 0.f, pss = 0.f;
#pragma unroll
        for (int i = 0; i < 4; i++)
#pragma unroll
            for (int r = 0; r < 4; r++) {
                float v = acc[i][j][r] + bv[j];
                ps += v * msk[i][r];
                pss += v * v * msk[i][r];
            }
        ps  += __shfl_xor(ps, 16, 64);  ps  += __shfl_xor(ps, 32, 64);
        pss += __shfl_xor(pss, 16, 64); pss += __shfl_xor(pss, 32, 64);
        if (l < 16) {
            atomicAdd(&stats[n0 + no + j * 16 + l15], ps);
            atomicAdd(&stats[N + n0 + no + j * 16 + l15], pss);
        }
    }

    short* Cs = SH;
#pragma unroll
    for (int pass = 0; pass < 2; pass++) {
        __syncthreads();
        if (wr == pass) {
#pragma unroll
            for (int j = 0; j < 4; j++)
#pragma unroll
                for (int i = 0; i < 4; i++)
#pragma unroll
                    for (int r = 0; r < 4; r++)
                        Cs[(i * 16 + quad * 4 + r) * 132 + no + j * 16 + l15] =
                            f2bf(acc[i][j][r] + bv[j]);
        }
        __syncthreads();
#pragma unroll
        for (int c = 0; c < 4; c++) {
            int e = c * 2048 + tid * 8;
            int row = e >> 7, col = e & 127;
            short8 vv = *(const short8*)(Cs + row * 132 + col);
            *(short8*)(Y + (long)(m0 + pass * 64 + row) * N + n0 + col) = vv;
        }
    }
}

// ---------------- fallback BT GEMM (R1: fused fp32 cvt staging) ------------
template<bool XBF16, bool KAL>
__global__ __launch_bounds__(256, 2)
void gemm_bt(const void* __restrict__ Xp, const float* __restrict__ W,
             const float* __restrict__ bias, short* __restrict__ Y,
             int N, int Kin, int Kp, float* __restrict__ stats,
             const int* __restrict__ lens, int Lshift)
{
    __shared__ short At[128 * 32];
    __shared__ short Bt[128 * 32];
    const int m0 = blockIdx.x * 128;
    const int n0 = blockIdx.y * 128;
    const int tid = threadIdx.x;
    const int w = tid >> 6, l = tid & 63;
    const int quad = l >> 4, l15 = l & 15;
    const int mo = (w & 1) * 64, no = (w >> 1) * 64;

    floatx4 acc[4][4];
#pragma unroll
    for (int i = 0; i < 4; i++)
#pragma unroll
        for (int j = 0; j < 4; j++) acc[i][j] = (floatx4){0.f, 0.f, 0.f, 0.f};

    const int srow = tid >> 2;
    const int sc8 = (tid & 3) * 8;

    for (int k0 = 0; k0 < Kp; k0 += 32) {
        __syncthreads();
        const int c0 = k0 + sc8;
        short8 a0, a1, b0, b1;
        if (XBF16) {
            const short* X = (const short*)Xp;
            a0 = *(const short8*)(X + (long)(m0 + srow) * Kp + c0);
            a1 = *(const short8*)(X + (long)(m0 + 64 + srow) * Kp + c0);
        } else {
            const float* X = (const float*)Xp;
            if (KAL) {
                a0 = cvt8load(X + (long)(m0 + srow) * Kin + c0);
                a1 = cvt8load(X + (long)(m0 + 64 + srow) * Kin + c0);
            } else {
                a0 = cvt8guard(X + (long)(m0 + srow) * Kin, c0, Kin);
                a1 = cvt8guard(X + (long)(m0 + 64 + srow) * Kin, c0, Kin);
            }
        }
        if (KAL) {
            b0 = cvt8load(W + (long)(n0 + srow) * Kin + c0);
            b1 = cvt8load(W + (long)(n0 + 64 + srow) * Kin + c0);
        } else {
            b0 = cvt8guard(W + (long)(n0 + srow) * Kin, c0, Kin);
            b1 = cvt8guard(W + (long)(n0 + 64 + srow) * Kin, c0, Kin);
        }
        *(short8*)(At + srow * 32 + sc8) = a0;
        *(short8*)(At + (64 + srow) * 32 + sc8) = a1;
        *(short8*)(Bt + srow * 32 + sc8) = b0;
        *(short8*)(Bt + (64 + srow) * 32 + sc8) = b1;
        __syncthreads();
        short8 af[4], bfr[4];
#pragma unroll
        for (int i = 0; i < 4; i++) {
            af[i]  = *(const short8*)(At + (mo + i * 16 + l15) * 32 + quad * 8);
            bfr[i] = *(const short8*)(Bt + (no + i * 16 + l15) * 32 + quad * 8);
        }
#pragma unroll
        for (int i = 0; i < 4; i++)
#pragma unroll
            for (int j = 0; j < 4; j++)
                acc[i][j] = __builtin_amdgcn_mfma_f32_16x16x32_bf16(af[i], bfr[j], acc[i][j], 0, 0, 0);
    }

    const int Lmask = (1 << Lshift) - 1;
    float msk[4][4];
#pragma unroll
    for (int i = 0; i < 4; i++)
#pragma unroll
        for (int r = 0; r < 4; r++) {
            int rg = m0 + mo + i * 16 + quad * 4 + r;
            msk[i][r] = ((rg & Lmask) < lens[rg >> Lshift]) ? 1.f : 0.f;
        }
#pragma unroll
    for (int j = 0; j < 4; j++) {
        int colj = n0 + no + j * 16 + l15;
        float bvs = bias[colj];
        float ps = 0.f, pss = 0.f;
#pragma unroll
        for (int i = 0; i < 4; i++)
#pragma unroll
            for (int r = 0; r < 4; r++) {
                int rg = m0 + mo + i * 16 + quad * 4 + r;
                float v = acc[i][j][r] + bvs;
                Y[(long)rg * N + colj] = f2bf(v);
                ps += v * msk[i][r];
                pss += v * v * msk[i][r];
            }
        ps  += __shfl_xor(ps, 16, 64);  ps  += __shfl_xor(ps, 32, 64);
        pss += __shfl_xor(pss, 16, 64); pss += __shfl_xor(pss, 32, 64);
        if (l < 16) {
            atomicAdd(&stats[colj], ps);
            atomicAdd(&stats[N + colj], pss);
        }
    }
}

// ---------------- finalize: stats -> {scale, shift} per channel ------------
__global__ void finalize_stats(float* __restrict__ stats, const float* __restrict__ g,
                               const float* __restrict__ beta,
                               const int* __restrict__ lens, int C)
{
    __shared__ int lred[256];
    int t = threadIdx.x;
    if (t < 256) lred[t] = lens[t];
    __syncthreads();
    for (int s2 = 128; s2 > 0; s2 >>= 1) {
        if (t < s2) lred[t] += lred[t + s2];
        __syncthreads();
    }
    float cnt = (float)lred[0];
    if (t < C) {
        float mean = stats[t] / cnt;
        float var = fmaxf(stats[C + t] / cnt - mean * mean, 0.f);
        float a = rsqrtf(var + 1e-5f) * g[t];
        stats[t] = a;
        stats[C + t] = beta[t] - mean * a;
    }
}

// ---------------- BN + relu + row L2-normalize, C=512, in place ------------
__global__ __launch_bounds__(256)
void apply_norm512(short* __restrict__ Y, const float* __restrict__ stats)
{
    int w = threadIdx.x >> 6, l = threadIdx.x & 63;
    long row = (long)blockIdx.x * 4 + w;
    short8 yv = *(const short8*)(Y + row * 512 + l * 8);
    float v[8];
    float ss = 0.f;
#pragma unroll
    for (int i = 0; i < 8; i++) {
        int c = l * 8 + i;
        float t = fmaxf(bf2f(yv[i]) * stats[c] + stats[512 + c], 0.f);
        v[i] = t;
        ss += t * t;
    }
#pragma unroll
    for (int off = 1; off < 64; off <<= 1) ss += __shfl_xor(ss, off, 64);
    float scl = 1.f / fmaxf(sqrtf(ss), 1e-12f);
    short8 o;
#pragma unroll
    for (int i = 0; i < 8; i++) o[i] = f2bf(v[i] * scl);
    *(short8*)(Y + row * 512 + l * 8) = o;
}

// k/v variant: early-exit blocks whose 4 rows are all beyond b_len (dead).
__global__ __launch_bounds__(256)
void apply_norm512_len(short* __restrict__ Y, const float* __restrict__ stats,
                       const int* __restrict__ lens)
{
    int bid = blockIdx.x;
    if (((bid & 127) * 4) >= lens[bid >> 7]) return;
    int w = threadIdx.x >> 6, l = threadIdx.x & 63;
    long row = (long)bid * 4 + w;
    short8 yv = *(const short8*)(Y + row * 512 + l * 8);
    float v[8];
    float ss = 0.f;
#pragma unroll
    for (int i = 0; i < 8; i++) {
        int c = l * 8 + i;
        float t = fmaxf(bf2f(yv[i]) * stats[c] + stats[512 + c], 0.f);
        v[i] = t;
        ss += t * t;
    }
#pragma unroll
    for (int off = 1; off < 64; off <<= 1) ss += __shfl_xor(ss, off, 64);
    float scl = 1.f / fmaxf(sqrtf(ss), 1e-12f);
    short8 o;
#pragma unroll
    for (int i = 0; i < 8; i++) o[i] = f2bf(v[i] * scl);
    *(short8*)(Y + row * 512 + l * 8) = o;
}

// ---------------- attention body, NT = number of live 32-row k/v tiles -----
// ALL register arrays (sc, pf, qf) indexed with compile-time constants.
template<int NT>
__device__ __forceinline__ void attn_body(
    short* __restrict__ tile, short* __restrict__ Pw,
    const short* __restrict__ qbase, const short* __restrict__ kbase,
    const short* __restrict__ vbase, short* __restrict__ wvbase,
    int blen, int tid, int quad, int l15, int wvStride)
{
    const int sr = tid >> 3;
    const int scg = (tid & 7) * 8;

    short8 qf[16];
#pragma unroll
    for (int kk = 0; kk < 16; kk++) qf[kk] = *(const short8*)(qbase + kk * 32);

    floatx4 sc[2 * NT];
#pragma unroll
    for (int i = 0; i < 2 * NT; i++) sc[i] = (floatx4){0.f, 0.f, 0.f, 0.f};

#pragma unroll
    for (int bt2 = 0; bt2 < NT; ++bt2) {
        __syncthreads();
        const short* krow = kbase + (long)(bt2 * 32 + sr) * 512;
#pragma unroll
        for (int i = 0; i < 2; i++) {
            short8 t0 = *(const short8*)(krow + i * 256 + scg);
            short8 t1 = *(const short8*)(krow + i * 256 + 64 + scg);
            short8 t2 = *(const short8*)(krow + i * 256 + 128 + scg);
            short8 t3 = *(const short8*)(krow + i * 256 + 192 + scg);
            *(short8*)(&tile[sr * 520 + i * 256 + scg]) = t0;
            *(short8*)(&tile[sr * 520 + i * 256 + 64 + scg]) = t1;
            *(short8*)(&tile[sr * 520 + i * 256 + 128 + scg]) = t2;
            *(short8*)(&tile[sr * 520 + i * 256 + 192 + scg]) = t3;
        }
        __syncthreads();
#pragma unroll
        for (int kk = 0; kk < 16; kk++) {
            short8 f0 = *(const short8*)(&tile[l15 * 520 + kk * 32 + quad * 8]);
            short8 f1 = *(const short8*)(&tile[(16 + l15) * 520 + kk * 32 + quad * 8]);
            sc[bt2 * 2]     = __builtin_amdgcn_mfma_f32_16x16x32_bf16(qf[kk], f0, sc[bt2 * 2], 0, 0, 0);
            sc[bt2 * 2 + 1] = __builtin_amdgcn_mfma_f32_16x16x32_bf16(qf[kk], f1, sc[bt2 * 2 + 1], 0, 0, 0);
        }
    }

    const float scaler = 6.25f;
    float mrow[4] = {-__builtin_inff(), -__builtin_inff(), -__builtin_inff(), -__builtin_inff()};
#pragma unroll
    for (int bt = 0; bt < 2 * NT; ++bt) {
        bool valid = (bt * 16 + l15) < blen;
#pragma unroll
        for (int r = 0; r < 4; r++) {
            float v2 = valid ? sc[bt][r] * scaler : -__builtin_inff();
            sc[bt][r] = v2;
            mrow[r] = fmaxf(mrow[r], v2);
        }
    }
#pragma unroll
    for (int r = 0; r < 4; r++) {
#pragma unroll
        for (int off = 1; off < 16; off <<= 1)
            mrow[r] = fmaxf(mrow[r], __shfl_xor(mrow[r], off, 64));
    }
    float ssum[4] = {0.f, 0.f, 0.f, 0.f};
#pragma unroll
    for (int bt = 0; bt < 2 * NT; ++bt)
#pragma unroll
        for (int r = 0; r < 4; r++) {
            float p = __expf(sc[bt][r] - mrow[r]);
            sc[bt][r] = p;
            ssum[r] += p;
        }
#pragma unroll
    for (int r = 0; r < 4; r++) {
#pragma unroll
        for (int off = 1; off < 16; off <<= 1) ssum[r] += __shfl_xor(ssum[r], off, 64);
        ssum[r] = 1.f / ssum[r];
    }

    short8 pf[NT];
#pragma unroll
    for (int kk = 0; kk < NT; kk++) {
#pragma unroll
        for (int half = 0; half < 2; half++)
#pragma unroll
            for (int r = 0; r < 4; r++)
                Pw[(quad * 4 + r) * 40 + half * 16 + l15] = f2bf(sc[kk * 2 + half][r] * ssum[r]);
        pf[kk] = *(const short8*)(&Pw[l15 * 40 + quad * 8]);
    }

    // phase 2: wv[a][d] = sum_{b<NT*32} P[a][b] v[b][d]  (P=0 beyond blen)
    for (int dt = 0; dt < 16; ++dt) {
        __syncthreads();
#pragma unroll
        for (int round = 0; round < 2; round++) {
            int b = round * 256 + tid;
            if (NT == 16 || b < NT * 32) {
                const short* vr = vbase + (long)b * 512 + dt * 32;
                short8 x0 = *(const short8*)(vr);
                short8 x1 = *(const short8*)(vr + 8);
                short8 x2 = *(const short8*)(vr + 16);
                short8 x3 = *(const short8*)(vr + 24);
#pragma unroll
                for (int j = 0; j < 8; j++) {
                    tile[j * 520 + b]        = x0[j];
                    tile[(8 + j) * 520 + b]  = x1[j];
                    tile[(16 + j) * 520 + b] = x2[j];
                    tile[(24 + j) * 520 + b] = x3[j];
                }
            }
        }
        __syncthreads();
        floatx4 o0 = (floatx4){0.f, 0.f, 0.f, 0.f};
        floatx4 o1 = (floatx4){0.f, 0.f, 0.f, 0.f};
#pragma unroll
        for (int kk = 0; kk < NT; kk++) {
            short8 f0 = *(const short8*)(&tile[l15 * 520 + kk * 32 + quad * 8]);
            short8 f1 = *(const short8*)(&tile[(16 + l15) * 520 + kk * 32 + quad * 8]);
            o0 = __builtin_amdgcn_mfma_f32_16x16x32_bf16(pf[kk], f0, o0, 0, 0, 0);
            o1 = __builtin_amdgcn_mfma_f32_16x16x32_bf16(pf[kk], f1, o1, 0, 0, 0);
        }
#pragma unroll
        for (int r = 0; r < 4; r++) {
            wvbase[(long)r * wvStride + dt * 32 + l15]      = f2bf(o0[r]);
            wvbase[(long)r * wvStride + dt * 32 + 16 + l15] = f2bf(o1[r]);
        }
    }
}

// ---------------- attention: per (s, 64 a-rows) block, XCD-swizzled --------
__global__ __launch_bounds__(256)
void attention(const short* __restrict__ q, const short* __restrict__ k,
               const short* __restrict__ v, const int* __restrict__ b_lens,
               const int* __restrict__ a_lens,
               short* __restrict__ wv, int wvStride)
{
    __shared__ short tile[32 * 520];
    __shared__ short Pscr[4][16 * 40];
    const int lin = blockIdx.x;
    const int xcd = lin & 7, sl = lin >> 3;
    const int a0 = (sl & 1) * 64;
    const int s = (sl >> 1) * 8 + xcd;
    const int tid = threadIdx.x;
    const int w = tid >> 6, l = tid & 63;
    const int quad = l >> 4, l15 = l & 15;
    const int blen = b_lens[s];

    // dead a-half: zero-fill wv rows (finite for f-gemm) and exit
    if (a_lens[s] <= a0) {
        short8 z = (short8){0, 0, 0, 0, 0, 0, 0, 0};
        short* wz = wv + (long)(s * 128 + a0) * wvStride;
        const int total = 64 * wvStride;
        for (int e = tid * 8; e < total; e += 2048)
            *(short8*)(wz + e) = z;
        return;
    }

    const short* qbase = q + ((long)(s * 128 + a0 + w * 16 + l15)) * 512 + quad * 8;
    const short* kbase = k + (long)s * 512 * 512;
    const short* vbase = v + (long)s * 512 * 512;
    short* wvbase = wv + (long)(s * 128 + a0 + w * 16 + quad * 4) * wvStride;
    short* Pw = Pscr[w];

    const int grp = (blen + 127) >> 7;   // 1..4 live 128-row groups
    if (grp == 1)
        attn_body<4>(tile, Pw, qbase, kbase, vbase, wvbase, blen, tid, quad, l15, wvStride);
    else if (grp == 2)
        attn_body<8>(tile, Pw, qbase, kbase, vbase, wvbase, blen, tid, quad, l15, wvStride);
    else if (grp == 3)
        attn_body<12>(tile, Pw, qbase, kbase, vbase, wvbase, blen, tid, quad, l15, wvStride);
    else
        attn_body<16>(tile, Pw, qbase, kbase, vbase, wvbase, blen, tid, quad, l15, wvStride);

    // zero wv pad columns (K-pad for the f-gemm)
    if (wvStride > 512) {
        int r = tid >> 2, cb = (tid & 3) * 16;
        short8 z = (short8){0, 0, 0, 0, 0, 0, 0, 0};
        short* pz = wv + (long)(s * 128 + a0 + r) * wvStride + 512 + cb;
        *(short8*)(pz) = z;
        *(short8*)(pz + 8) = z;
    }
}

// ---------------- f: BN + relu + mask_a -> d_out fp32 ----------------------
__global__ __launch_bounds__(256)
void apply_f(const short* __restrict__ Yf, const float* __restrict__ stats,
             const int* __restrict__ a_lens, float* __restrict__ out)
{
    const long total = (long)32768 * 256;
    for (long e = (long)blockIdx.x * 256 + threadIdx.x; e < total; e += (long)gridDim.x * 256) {
        int c = (int)(e & 255);
        long row = e >> 8;
        int sI = (int)(row >> 7), pos = (int)(row & 127);
        float v = fmaxf(bf2f(Yf[e]) * stats[c] + stats[256 + c], 0.f);
        out[e] = (pos < a_lens[sI]) ? v : 0.f;
    }
}

// ---------------------------------------------------------------------------
extern "C" void kernel_launch(void* const* d_in, const int* in_sizes, int n_in,
                              void* d_out, int out_size, void* d_ws, size_t ws_size,
                              hipStream_t stream)
{
    (void)in_sizes; (void)n_in; (void)out_size;
    const float* A     = (const float*)d_in[0];
    const float* B     = (const float*)d_in[1];
    const int* a_lens  = (const int*)d_in[2];
    const int* b_lens  = (const int*)d_in[3];
    const float* Wq    = (const float*)d_in[4];
    const float* bq    = (const float*)d_in[5];
    const float* gq    = (const float*)d_in[6];
    const float* betaq = (const float*)d_in[7];
    const float* Wk    = (const float*)d_in[8];
    const float* bk    = (const float*)d_in[9];
    const float* gk    = (const float*)d_in[10];
    const float* betak = (const float*)d_in[11];
    const float* Wv    = (const float*)d_in[12];
    const float* bv    = (const float*)d_in[13];
    const float* gv    = (const float*)d_in[14];
    const float* betav = (const float*)d_in[15];
    const float* Wf    = (const float*)d_in[16];
    const float* bfp   = (const float*)d_in[17];
    const float* gf    = (const float*)d_in[18];
    const float* betaf = (const float*)d_in[19];
    float* out = (float*)d_out;
    char* base = (char*)d_ws;

    const size_t oWqb = 0;
    const size_t oWkb = oWqb + 294912;
    const size_t oWvb = oWkb + 294912;
    const size_t oWfb = oWvb + 294912;
    const size_t oBbf = oWfb + 294912;
    const size_t oQb  = oBbf + 75497472;
    const size_t oYv  = oQb + 33554432;
    const size_t oKb  = oYv + 134217728;
    const size_t oSt  = oKb + 134217728;
    const size_t FAST_NEED = oSt + 16384;

    if (ws_size >= FAST_NEED) {
        short* Wqb = (short*)(base + oWqb);
        short* Wkb = (short*)(base + oWkb);
        short* Wvb = (short*)(base + oWvb);
        short* Wfb = (short*)(base + oWfb);
        short* Bbf = (short*)(base + oBbf);
        short* qb  = (short*)(base + oQb);
        short* Yv  = (short*)(base + oYv);
        short* kb  = (short*)(base + oKb);
        short* Abf = (short*)(base + oKb);
        short* wvb = (short*)(base + oBbf);
        short* Yf  = (short*)(base + oQb);
        float* stQ = (float*)(base + oSt);
        float* stK = stQ + 1024;
        float* stV = stQ + 2048;
        float* stF = stQ + 3072;

        hipMemsetAsync(stQ, 0, 16384, stream);

        cvt_pad<<<32768, 256, 0, stream>>>(A, Abf, 256, 288);
        cvt_padB<<<131072, 256, 0, stream>>>(B, Bbf, 265, 288, b_lens);
        cvt_pad<<<512, 256, 0, stream>>>(Wq, Wqb, 256, 288);
        cvt_pad<<<512, 256, 0, stream>>>(Wk, Wkb, 265, 288);
        cvt_pad<<<512, 256, 0, stream>>>(Wv, Wvb, 265, 288);
        cvt_pad<<<256, 256, 0, stream>>>(Wf, Wfb, 512, 576);

        // q projection: 256 m-tiles x 4 n-blocks, swizzled
        gemm128<<<1024, 256, 0, stream>>>(
            Abf, Wqb, Wqb, bq, bq, qb, qb, stQ, stQ, 512, 288, a_lens, 7, 2, 0);
        // fused k+v with dead-tile skip (clobbers Abf)
        gemm128x2<<<4096, 256, 0, stream>>>(
            Bbf, Wvb, Wkb, bv, bk, Yv, kb, stV, stK, 512, 288, b_lens, 9, 2);

        finalize_stats<<<1, 512, 0, stream>>>(stV, gv, betav, b_lens, 512);
        finalize_stats<<<1, 512, 0, stream>>>(stK, gk, betak, b_lens, 512);
        finalize_stats<<<1, 512, 0, stream>>>(stQ, gq, betaq, a_lens, 512);
        apply_norm512_len<<<32768, 256, 0, stream>>>(Yv, stV, b_lens);
        apply_norm512_len<<<32768, 256, 0, stream>>>(kb, stK, b_lens);
        apply_norm512<<<8192, 256, 0, stream>>>(qb, stQ);

        attention<<<512, 256, 0, stream>>>(qb, kb, Yv, b_lens, a_lens, wvb, 576);

        gemm128<<<512, 256, 0, stream>>>(
            wvb, Wfb, Wfb, bfp, bfp, Yf, Yf, stF, stF, 256, 576, a_lens, 7, 1, 0);
        finalize_stats<<<1, 512, 0, stream>>>(stF, gf, betaf, a_lens, 256);
        apply_f<<<8192, 256, 0, stream>>>(Yf, stF, a_lens, out);
        return;
    }

    // ---- fallback: R1-style path (known correct) ----
    short* qb  = (short*)(base);
    short* Yv  = (short*)(base + 33554432);
    short* kb  = (short*)(base + 33554432 + 134217728);
    short* wvb = (short*)(base + 33554432 + 2L * 134217728);
    float* stQ = (float*)(base + 2L * 33554432 + 2L * 134217728);
    float* stK = stQ + 1024;
    float* stV = stQ + 2048;
    float* stF = stQ + 3072;
    short* Yf  = qb;

    hipMemsetAsync(stQ, 0, 16384, stream);

    gemm_bt<false, true><<<dim3(256, 4), 256, 0, stream>>>(
        A, Wq, bq, qb, 512, 256, 256, stQ, a_lens, 7);
    gemm_bt<false, false><<<dim3(1024, 4), 256, 0, stream>>>(
        B, Wv, bv, Yv, 512, 265, 288, stV, b_lens, 9);
    finalize_stats<<<1, 512, 0, stream>>>(stV, gv, betav, b_lens, 512);
    apply_norm512<<<32768, 256, 0, stream>>>(Yv, stV);
    gemm_bt<false, false><<<dim3(1024, 4), 256, 0, stream>>>(
        B, Wk, bk, kb, 512, 265, 288, stK, b_lens, 9);
    finalize_stats<<<1, 512, 0, stream>>>(stK, gk, betak, b_lens, 512);
    apply_norm512<<<32768, 256, 0, stream>>>(kb, stK);
    finalize_stats<<<1, 512, 0, stream>>>(stQ, gq, betaq, a_lens, 512);
    apply_norm512<<<8192, 256, 0, stream>>>(qb, stQ);
    attention<<<512, 256, 0, stream>>>(qb, kb, Yv, b_lens, a_lens, wvb, 512);
    gemm_bt<true, true><<<dim3(256, 2), 256, 0, stream>>>(
        wvb, Wf, bfp, Yf, 256, 512, 512, stF, a_lens, 7);
    finalize_stats<<<1, 512, 0, stream>>>(stF, gf, betaf, a_lens, 256);
    apply_f<<<8192, 256, 0, stream>>>(Yf, stF, a_lens, out);
}